// Round 1
// baseline (980.254 us; speedup 1.0000x reference)
//
#include <hip/hip_runtime.h>
#include <hip/hip_bf16.h>

#define NH 8
#define DH 64
#define NPIX 1024
#define CIN 64
#define NBH 64
#define QSCALE 512.0f

__device__ __forceinline__ float wred_max(float v) {
  #pragma unroll
  for (int o = 32; o; o >>= 1) v = fmaxf(v, __shfl_xor(v, o, 64));
  return v;
}
__device__ __forceinline__ float wred_sum(float v) {
  #pragma unroll
  for (int o = 32; o; o >>= 1) v += __shfl_xor(v, o, 64);
  return v;
}

// ---------------- QKV projection ----------------
// qkv[b][o][p] = sum_c w[o][c] * x[b][c][p];  q scaled by 512.
// Store per-head layout: T[((b*8+h)*1024 + p)*64 + d]
// grid: (4 p-tiles, 48 o-groups of 32, 8 b), block 256
__global__ __launch_bounds__(256) void qkv_proj(
    const float* __restrict__ x, const float* __restrict__ wqkv,
    float* __restrict__ Q, float* __restrict__ K, float* __restrict__ V) {
  int p = blockIdx.x * 256 + threadIdx.x;
  int o0 = blockIdx.y * 32;
  int b = blockIdx.z;
  const float* xb = x + ((size_t)b * CIN) * NPIX + p;
  float acc[32];
  #pragma unroll
  for (int oo = 0; oo < 32; ++oo) acc[oo] = 0.f;
  #pragma unroll 8
  for (int c = 0; c < CIN; ++c) {
    float xv = xb[(size_t)c * NPIX];
    const float* wrow = wqkv + (size_t)o0 * CIN + c;
    #pragma unroll
    for (int oo = 0; oo < 32; ++oo)
      acc[oo] = fmaf(wrow[oo * CIN], xv, acc[oo]);
  }
  int part = o0 >> 9;          // 0=q 1=k 2=v
  int h = (o0 >> 6) & 7;
  int d0 = o0 & 63;            // 0 or 32
  float* dst = part == 0 ? Q : (part == 1 ? K : V);
  float scl = part == 0 ? QSCALE : 1.0f;
  size_t base = (((size_t)(b * NH + h)) * NPIX + p) * DH + d0;
  #pragma unroll
  for (int oo = 0; oo < 32; ++oo) dst[base + oo] = acc[oo] * scl;
}

// ---------------- fused attention ----------------
// One block: one (b,h), 64 query rows. 8 waves; wave w owns rows 8w..8w+7
// (register-blocked per lane). Flash-style online softmax over 16 j-tiles.
// grid: 64 bh * 16 row-blocks = 1024 blocks, 512 threads.
__global__ __launch_bounds__(512) void attn_fused(
    const float* __restrict__ Q, const float* __restrict__ K,
    const float* __restrict__ V,
    const float* __restrict__ rel_h, const float* __restrict__ rel_w,
    float* __restrict__ out) {
  __shared__ float lhw[64][128];   // [row][0..62]=lh, [64+0..62]=lw   32KB
  __shared__ float kT[64][65];     // [c][j] (pad: 2-way max)          16.25KB
  __shared__ float vT[64][65];     // [j][d]                           16.25KB
  __shared__ float pbuf[8][8][64]; // [wave][r][j]                     16KB

  int tid = threadIdx.x;
  int lane = tid & 63;
  int w = tid >> 6;
  int bh = blockIdx.x >> 4;
  int i0 = (blockIdx.x & 15) << 6;

  const float* Qb = Q + (size_t)bh * NPIX * DH;
  const float* Kb = K + (size_t)bh * NPIX * DH;
  const float* Vb = V + (size_t)bh * NPIX * DH;

  int myrow0 = __builtin_amdgcn_readfirstlane((tid >> 6) << 3);

  // ---- relative-position logits: lh[row][s]=q_row.rel_h[s], lw likewise ----
  // pass p: slot = p*64+lane, table row = lane (lanes 0..62 valid)
  {
    int lr = lane < 63 ? lane : 62;
    #pragma unroll
    for (int p = 0; p < 2; ++p) {
      const float* tab = p == 0 ? rel_h : rel_w;
      float4 rr4[16];
      #pragma unroll
      for (int c4 = 0; c4 < 16; ++c4)
        rr4[c4] = *(const float4*)(tab + (size_t)lr * DH + c4 * 4);
      #pragma unroll
      for (int r = 0; r < 8; ++r) {
        int row = myrow0 + r;
        const float* qrow = Qb + (size_t)(i0 + row) * DH;  // uniform -> s_load
        float acc = 0.f;
        #pragma unroll
        for (int c4 = 0; c4 < 16; ++c4) {
          float4 q4 = *(const float4*)(qrow + c4 * 4);
          acc += q4.x * rr4[c4].x + q4.y * rr4[c4].y +
                 q4.z * rr4[c4].z + q4.w * rr4[c4].w;
        }
        if (lane < 63) lhw[row][p * 64 + lane] = acc;
      }
    }
  }

  // per-row state (lane&31 plays the xj role for the lw term)
  float m_r[8], l_r[8], o_acc[8], lwv[8];
  int lhbase[8];
  #pragma unroll
  for (int r = 0; r < 8; ++r) {
    int i_abs = i0 + myrow0 + r;
    int xi = i_abs & 31;
    int yi = (i_abs >> 5) & 31;
    lwv[r] = lhw[myrow0 + r][64 + 31 + (lane & 31) - xi];
    lhbase[r] = 31 - yi;
    m_r[r] = -3e30f; l_r[r] = 0.f; o_acc[r] = 0.f;
  }

  #pragma unroll 1
  for (int t = 0; t < 16; ++t) {
    __syncthreads();   // previous tile fully consumed
    int j0 = t << 6;
    // stage K (transposed) + V tiles, coalesced global f4 reads
    #pragma unroll
    for (int it = 0; it < 2; ++it) {
      int fi = tid + it * 512;
      int j = fi >> 4, c4 = fi & 15;
      float4 kv = *(const float4*)(Kb + (size_t)(j0 + j) * DH + c4 * 4);
      kT[c4 * 4 + 0][j] = kv.x;
      kT[c4 * 4 + 1][j] = kv.y;
      kT[c4 * 4 + 2][j] = kv.z;
      kT[c4 * 4 + 3][j] = kv.w;
      float4 vv = *(const float4*)(Vb + (size_t)(j0 + j) * DH + c4 * 4);
      vT[j][c4 * 4 + 0] = vv.x;
      vT[j][c4 * 4 + 1] = vv.y;
      vT[j][c4 * 4 + 2] = vv.z;
      vT[j][c4 * 4 + 3] = vv.w;
    }
    __syncthreads();

    // S = q.k   (lane = local j)
    float s_acc[8];
    #pragma unroll
    for (int r = 0; r < 8; ++r) s_acc[r] = 0.f;
    #pragma unroll
    for (int c4 = 0; c4 < 16; ++c4) {
      float k0 = kT[c4 * 4 + 0][lane];
      float k1 = kT[c4 * 4 + 1][lane];
      float k2 = kT[c4 * 4 + 2][lane];
      float k3 = kT[c4 * 4 + 3][lane];
      #pragma unroll
      for (int r = 0; r < 8; ++r) {
        float4 q4 = *(const float4*)(Qb + (size_t)(i0 + myrow0 + r) * DH + c4 * 4);
        s_acc[r] = fmaf(q4.x, k0, fmaf(q4.y, k1,
                   fmaf(q4.z, k2, fmaf(q4.w, k3, s_acc[r]))));
      }
    }

    // bias + online softmax (per row)
    int yj = (t << 1) + (lane >> 5);
    #pragma unroll
    for (int r = 0; r < 8; ++r) {
      float sv = s_acc[r] + lwv[r] + lhw[myrow0 + r][lhbase[r] + yj];
      float tm = wred_max(sv);
      float mnew = fmaxf(m_r[r], tm);
      float p = __expf(sv - mnew);
      float corr = __expf(m_r[r] - mnew);
      float psum = wred_sum(p);
      l_r[r] = l_r[r] * corr + psum;
      o_acc[r] *= corr;
      m_r[r] = mnew;
      pbuf[w][r][lane] = p;
    }
    __builtin_amdgcn_wave_barrier();  // keep p writes before p reads (same wave)

    // PV  (lane = d)
    #pragma unroll
    for (int j4 = 0; j4 < 16; ++j4) {
      float v0 = vT[j4 * 4 + 0][lane];
      float v1 = vT[j4 * 4 + 1][lane];
      float v2 = vT[j4 * 4 + 2][lane];
      float v3 = vT[j4 * 4 + 3][lane];
      #pragma unroll
      for (int r = 0; r < 8; ++r) {
        float4 p4 = *(const float4*)&pbuf[w][r][j4 * 4];
        o_acc[r] = fmaf(p4.x, v0, fmaf(p4.y, v1,
                   fmaf(p4.z, v2, fmaf(p4.w, v3, o_acc[r]))));
      }
    }
  }

  // epilogue: normalize, transpose via LDS, coalesced global write
  __syncthreads();
  #pragma unroll
  for (int r = 0; r < 8; ++r)
    kT[lane][myrow0 + r] = o_acc[r] / l_r[r];   // kT reused as [d][row]
  __syncthreads();
  int b = bh >> 3, h = bh & 7;
  #pragma unroll
  for (int it = 0; it < 2; ++it) {
    int fi = tid + it * 512;
    int d = fi >> 4, r4 = (fi & 15) << 2;
    float4 val = make_float4(kT[d][r4], kT[d][r4 + 1], kT[d][r4 + 2], kT[d][r4 + 3]);
    *(float4*)(out + (((size_t)(b * 512 + h * 64 + d)) << 10) + i0 + r4) = val;
  }
}

extern "C" void kernel_launch(void* const* d_in, const int* in_sizes, int n_in,
                              void* d_out, int out_size, void* d_ws, size_t ws_size,
                              hipStream_t stream) {
  const float* x  = (const float*)d_in[0];
  const float* wq = (const float*)d_in[1];
  const float* rh = (const float*)d_in[2];
  const float* rw = (const float*)d_in[3];
  float* out = (float*)d_out;

  float* Q = (float*)d_ws;                       // 64*1024*64 floats each
  float* K = Q + (size_t)NBH * NPIX * DH;
  float* V = K + (size_t)NBH * NPIX * DH;

  qkv_proj<<<dim3(4, 48, 8), 256, 0, stream>>>(x, wq, Q, K, V);
  attn_fused<<<dim3(NBH * 16), 512, 0, stream>>>(Q, K, V, rh, rw, out);
}

// Round 3
// 153.948 us; speedup vs baseline: 6.3674x; 6.3674x over previous
//
#include <hip/hip_runtime.h>
#include <hip/hip_bf16.h>
#include <hip/hip_fp16.h>

typedef _Float16 h8 __attribute__((ext_vector_type(8)));
typedef float f4 __attribute__((ext_vector_type(4)));

#define NH 8
#define DH 64
#define NPIX 1024
#define CIN 64
#define NBH 64
#define QSCALE 512.0f
#define LOSCALE 2048.0f
#define INV_LOSCALE (1.0f / 2048.0f)

// ---------------- QKV projection (fp16 hi/lo out) ----------------
__global__ __launch_bounds__(256) void qkv_proj(
    const float* __restrict__ x, const float* __restrict__ wqkv,
    _Float16* __restrict__ Qh, _Float16* __restrict__ Ql,
    _Float16* __restrict__ Kh, _Float16* __restrict__ Kl,
    _Float16* __restrict__ V) {
  int p = blockIdx.x * 256 + threadIdx.x;
  int o0 = blockIdx.y * 32;
  int b = blockIdx.z;
  const float* xb = x + ((size_t)b * CIN) * NPIX + p;
  float acc[32];
  #pragma unroll
  for (int oo = 0; oo < 32; ++oo) acc[oo] = 0.f;
  #pragma unroll 8
  for (int c = 0; c < CIN; ++c) {
    float xv = xb[(size_t)c * NPIX];
    const float* wrow = wqkv + (size_t)o0 * CIN + c;
    #pragma unroll
    for (int oo = 0; oo < 32; ++oo)
      acc[oo] = fmaf(wrow[oo * CIN], xv, acc[oo]);
  }
  int part = o0 >> 9;          // 0=q 1=k 2=v
  int h = (o0 >> 6) & 7;
  int d0 = o0 & 63;            // 0 or 32
  float scl = part == 0 ? QSCALE : 1.0f;
  _Float16* dhi = part == 0 ? Qh : (part == 1 ? Kh : V);
  _Float16* dlo = part == 0 ? Ql : (part == 1 ? Kl : nullptr);
  size_t base = (((size_t)(b * NH + h)) * NPIX + p) * DH + d0;
  _Float16 hv[32], lv[32];
  #pragma unroll
  for (int oo = 0; oo < 32; ++oo) {
    float a = acc[oo] * scl;
    _Float16 hi = (_Float16)a;
    hv[oo] = hi;
    lv[oo] = (_Float16)((a - (float)hi) * LOSCALE);
  }
  uint4* dv = (uint4*)(dhi + base);
  const uint4* sv = (const uint4*)hv;
  #pragma unroll
  for (int i = 0; i < 4; ++i) dv[i] = sv[i];
  if (dlo) {
    uint4* dv2 = (uint4*)(dlo + base);
    const uint4* sv2 = (const uint4*)lv;
    #pragma unroll
    for (int i = 0; i < 4; ++i) dv2[i] = sv2[i];
  }
}

// ---------------- fused MFMA attention (compensated fp16) ----------------
// Block: one (b,h) x 64 query rows. 4 waves, wave w owns rows w*16..w*16+15.
// 16 j-tiles of 64. LDS chunk layout: 128B rows, byte ^= ((row&7)<<4) swizzle.
__global__ __launch_bounds__(256) void attn_mfma(
    const _Float16* __restrict__ Qh, const _Float16* __restrict__ Ql,
    const _Float16* __restrict__ Kh, const _Float16* __restrict__ Kl,
    const _Float16* __restrict__ V,
    const float* __restrict__ rel_h, const float* __restrict__ rel_w,
    float* __restrict__ out) {
  __shared__ __align__(16) char SMem[49152];
  char* SMkh = SMem;                   // 8KB K-hi chunks [64 j][8 oct*16B]
  char* SMkl = SMem + 8192;            // 8KB K-lo chunks
  char* SMv  = SMem + 16384;           // 8KB V chunks [64 d][8 joct*16B]
  char* SMp  = SMem + 24576;           // 8KB P (2KB/wave)
  float* LH  = (float*)(SMem + 32768); // [64][64] f32 lh table (16KB)
  float* LWT = (float*)SMem;           // temp f32 [64][64] (over Khi+Klo)
  float* OT  = (float*)(SMem + 32768); // epilogue reuse of LH

  const int tid = threadIdx.x;
  const int lane = tid & 63;
  const int w = tid >> 6;       // wave 0..3
  const int c = lane & 15;
  const int g = lane >> 4;      // 0..3
  const int bh = blockIdx.x >> 4;
  const int i0 = (blockIdx.x & 15) << 6;

  const _Float16* Qhg = Qh + (size_t)bh * NPIX * DH;
  const _Float16* Qlg = Ql + (size_t)bh * NPIX * DH;
  const _Float16* Khg = Kh + (size_t)bh * NPIX * DH;
  const _Float16* Klg = Kl + (size_t)bh * NPIX * DH;
  const _Float16* Vg  = V  + (size_t)bh * NPIX * DH;

  // Q fragments: A row = lane%16, k-octet = kh*4 + g (same slot->d map as B)
  const h8* Qrowh = (const h8*)(Qhg + (size_t)(i0 + w * 16 + c) * DH);
  const h8* Qrowl = (const h8*)(Qlg + (size_t)(i0 + w * 16 + c) * DH);
  h8 qh0 = Qrowh[g], qh1 = Qrowh[4 + g];
  h8 ql0 = Qrowl[g], ql1 = Qrowl[4 + g];

  // ---- stage rel tables as fp16 chunks (rows s, swizzled) ----
  #pragma unroll
  for (int it = 0; it < 2; ++it) {
    int task = tid + it * 256;
    int oct = task & 7, s = task >> 3;
    int ss = s < 63 ? s : 62;
    const float* sh = rel_h + (size_t)ss * DH + oct * 8;
    const float* sw = rel_w + (size_t)ss * DH + oct * 8;
    h8 hh, ww;
    #pragma unroll
    for (int e = 0; e < 8; ++e) {
      hh[e] = (_Float16)sh[e];
      ww[e] = (_Float16)sw[e];
    }
    *(h8*)(SMkh + s * 128 + ((oct ^ (s & 7)) << 4)) = hh;
    *(h8*)(SMv + s * 128 + ((oct ^ (s & 7)) << 4)) = ww;
  }
  __syncthreads();

  // ---- lh/lw logit tables via MFMA (with Qlo correction) ----
  f4 zf = {0.f, 0.f, 0.f, 0.f};
  f4 lhC[4], lwC[4], lhCc[4], lwCc[4];
  #pragma unroll
  for (int cg = 0; cg < 4; ++cg) { lhC[cg] = zf; lwC[cg] = zf; lhCc[cg] = zf; lwCc[cg] = zf; }
  #pragma unroll
  for (int kh = 0; kh < 2; ++kh) {
    h8 a  = kh == 0 ? qh0 : qh1;
    h8 al = kh == 0 ? ql0 : ql1;
    #pragma unroll
    for (int cg = 0; cg < 4; ++cg) {
      int s = cg * 16 + c;
      h8 rb = *(const h8*)(SMkh + s * 128 + (((kh * 4 + g) ^ (s & 7)) << 4));
      lhC[cg]  = __builtin_amdgcn_mfma_f32_16x16x32_f16(a,  rb, lhC[cg], 0, 0, 0);
      lhCc[cg] = __builtin_amdgcn_mfma_f32_16x16x32_f16(al, rb, lhCc[cg], 0, 0, 0);
      h8 wb = *(const h8*)(SMv + s * 128 + (((kh * 4 + g) ^ (s & 7)) << 4));
      lwC[cg]  = __builtin_amdgcn_mfma_f32_16x16x32_f16(a,  wb, lwC[cg], 0, 0, 0);
      lwCc[cg] = __builtin_amdgcn_mfma_f32_16x16x32_f16(al, wb, lwCc[cg], 0, 0, 0);
    }
  }
  #pragma unroll
  for (int cg = 0; cg < 4; ++cg)
    #pragma unroll
    for (int reg = 0; reg < 4; ++reg)
      LH[(w * 16 + 4 * g + reg) * 64 + cg * 16 + c] =
          lhC[cg][reg] + lhCc[cg][reg] * INV_LOSCALE;
  __syncthreads();   // rel chunks fully consumed
  #pragma unroll
  for (int cg = 0; cg < 4; ++cg)
    #pragma unroll
    for (int reg = 0; reg < 4; ++reg)
      LWT[(w * 16 + 4 * g + reg) * 64 + cg * 16 + c] =
          lwC[cg][reg] + lwCc[cg][reg] * INV_LOSCALE;

  // lw values needed forever: row (4g+reg), xj in {c, 16+c} (own-wave rows)
  float lwreg[4][2];
  #pragma unroll
  for (int reg = 0; reg < 4; ++reg) {
    int r = w * 16 + 4 * g + reg;
    int xi = r & 31;
    #pragma unroll
    for (int par = 0; par < 2; ++par)
      lwreg[reg][par] = LWT[r * 64 + 31 + par * 16 + c - xi];
  }

  const int yi = (i0 + w * 16) >> 5;   // uniform per wave
  float m_s[4], l_s[4];
  f4 o_[4];
  #pragma unroll
  for (int reg = 0; reg < 4; ++reg) { m_s[reg] = -1e30f; l_s[reg] = 0.f; }
  #pragma unroll
  for (int cg = 0; cg < 4; ++cg) o_[cg] = zf;

  #pragma unroll 1
  for (int t = 0; t < 16; ++t) {
    const int j0 = t << 6;
    __syncthreads();   // prev tile consumed (and LWT consumed at t=0)

    // stage K hi+lo chunks: chunk(j, oct) = K[j0+j][8oct..8oct+7]
    #pragma unroll
    for (int it = 0; it < 2; ++it) {
      int task = tid + it * 256;
      int oct = task & 7, j = task >> 3;
      h8 kvh = *(const h8*)(Khg + (size_t)(j0 + j) * DH + oct * 8);
      h8 kvl = *(const h8*)(Klg + (size_t)(j0 + j) * DH + oct * 8);
      *(h8*)(SMkh + j * 128 + ((oct ^ (j & 7)) << 4)) = kvh;
      *(h8*)(SMkl + j * 128 + ((oct ^ (j & 7)) << 4)) = kvl;
    }
    // stage V transposed chunks: chunk(d, joct) = V[j0+8*joct..][d]
    #pragma unroll
    for (int it = 0; it < 2; ++it) {
      int task = tid + it * 256;
      int j = task & 63, dd = task >> 6;   // dd 0..7 across both its
      h8 vv = *(const h8*)(Vg + (size_t)(j0 + j) * DH + dd * 8);
      #pragma unroll
      for (int e = 0; e < 8; ++e) {
        int d = dd * 8 + e;
        *(_Float16*)(SMv + d * 128 + (((j >> 3) ^ (d & 7)) << 4) + (j & 7) * 2) = vv[e];
      }
    }
    __syncthreads();

    // QK^T -> S (row = 4g+reg, col j = 16cg+c), compensated
    f4 s_[4], sc_[4];
    #pragma unroll
    for (int cg = 0; cg < 4; ++cg) { s_[cg] = zf; sc_[cg] = zf; }
    #pragma unroll
    for (int kh = 0; kh < 2; ++kh) {
      h8 a  = kh == 0 ? qh0 : qh1;
      h8 al = kh == 0 ? ql0 : ql1;
      #pragma unroll
      for (int cg = 0; cg < 4; ++cg) {
        int j = cg * 16 + c;
        h8 kbh = *(const h8*)(SMkh + j * 128 + (((kh * 4 + g) ^ (j & 7)) << 4));
        h8 kbl = *(const h8*)(SMkl + j * 128 + (((kh * 4 + g) ^ (j & 7)) << 4));
        s_[cg]  = __builtin_amdgcn_mfma_f32_16x16x32_f16(a,  kbh, s_[cg], 0, 0, 0);
        sc_[cg] = __builtin_amdgcn_mfma_f32_16x16x32_f16(al, kbh, sc_[cg], 0, 0, 0);
        sc_[cg] = __builtin_amdgcn_mfma_f32_16x16x32_f16(a,  kbl, sc_[cg], 0, 0, 0);
      }
    }

    // bias: + correction + lh[row][31 + yj - yi] + lw[row][31 + xj - xi]
    float lhv[4][2];
    #pragma unroll
    for (int reg = 0; reg < 4; ++reg) {
      int r = w * 16 + 4 * g + reg;
      int base = 31 + 2 * t - yi;
      lhv[reg][0] = LH[r * 64 + base];
      lhv[reg][1] = LH[r * 64 + base + 1];
    }
    #pragma unroll
    for (int cg = 0; cg < 4; ++cg)
      #pragma unroll
      for (int reg = 0; reg < 4; ++reg)
        s_[cg][reg] += sc_[cg][reg] * INV_LOSCALE + lwreg[reg][cg & 1] + lhv[reg][cg >> 1];

    // online softmax (row reduce across 16 lanes of the g-group)
    float p_[4][4];   // [cg][reg]
    float corr[4];
    #pragma unroll
    for (int reg = 0; reg < 4; ++reg) {
      float tm = fmaxf(fmaxf(s_[0][reg], s_[1][reg]), fmaxf(s_[2][reg], s_[3][reg]));
      #pragma unroll
      for (int off = 1; off <= 8; off <<= 1) tm = fmaxf(tm, __shfl_xor(tm, off, 64));
      float mn = fmaxf(m_s[reg], tm);
      corr[reg] = __expf(m_s[reg] - mn);
      m_s[reg] = mn;
      float ps = 0.f;
      #pragma unroll
      for (int cg = 0; cg < 4; ++cg) {
        float pv = __expf(s_[cg][reg] - mn);
        p_[cg][reg] = pv;
        ps += pv;
      }
      #pragma unroll
      for (int off = 1; off <= 8; off <<= 1) ps += __shfl_xor(ps, off, 64);
      l_s[reg] = l_s[reg] * corr[reg] + ps;
    }
    #pragma unroll
    for (int cg = 0; cg < 4; ++cg)
      #pragma unroll
      for (int reg = 0; reg < 4; ++reg)
        o_[cg][reg] *= corr[reg];

    // write P (fp16) to per-wave LDS, rows 4g+reg, col j = 16cg+c
    #pragma unroll
    for (int cg = 0; cg < 4; ++cg)
      #pragma unroll
      for (int reg = 0; reg < 4; ++reg) {
        int r = 4 * g + reg;
        int j = cg * 16 + c;
        *(_Float16*)(SMp + w * 2048 + r * 128 + (((j >> 3) ^ (r & 7)) << 4) + (j & 7) * 2)
            = (_Float16)p_[cg][reg];
      }
    __builtin_amdgcn_wave_barrier();

    // PV: A = P (row=c, k-octet kh*4+g), B = V chunks
    #pragma unroll
    for (int kh = 0; kh < 2; ++kh) {
      h8 pa = *(const h8*)(SMp + w * 2048 + c * 128 + (((kh * 4 + g) ^ (c & 7)) << 4));
      #pragma unroll
      for (int cgd = 0; cgd < 4; ++cgd) {
        int d = cgd * 16 + c;
        h8 vb = *(const h8*)(SMv + d * 128 + (((kh * 4 + g) ^ (d & 7)) << 4));
        o_[cgd] = __builtin_amdgcn_mfma_f32_16x16x32_f16(pa, vb, o_[cgd], 0, 0, 0);
      }
    }
  }

  // ---- epilogue: normalize, transpose via LDS (reuse LH area), store ----
  __syncthreads();
  #pragma unroll
  for (int cgd = 0; cgd < 4; ++cgd)
    #pragma unroll
    for (int reg = 0; reg < 4; ++reg) {
      int d = cgd * 16 + c;
      int r = w * 16 + 4 * g + reg;
      OT[d * 64 + (r ^ ((d & 7) << 3))] = o_[cgd][reg] / l_s[reg];
    }
  __syncthreads();
  #pragma unroll
  for (int it = 0; it < 4; ++it) {
    int task = tid + it * 256;
    int rq = task & 15, d = task >> 4;
    f4 vv = *(const f4*)&OT[d * 64 + ((rq * 4) ^ ((d & 7) << 3))];
    *(f4*)(out + (((size_t)bh * 64 + d) << 10) + i0 + rq * 4) = vv;
  }
}

extern "C" void kernel_launch(void* const* d_in, const int* in_sizes, int n_in,
                              void* d_out, int out_size, void* d_ws, size_t ws_size,
                              hipStream_t stream) {
  const float* x  = (const float*)d_in[0];
  const float* wq = (const float*)d_in[1];
  const float* rh = (const float*)d_in[2];
  const float* rw = (const float*)d_in[3];
  float* out = (float*)d_out;

  const size_t sz = (size_t)NBH * NPIX * DH;   // 4M halves = 8MB each
  _Float16* Qh = (_Float16*)d_ws;
  _Float16* Ql = Qh + sz;
  _Float16* Kh = Ql + sz;
  _Float16* Kl = Kh + sz;
  _Float16* V  = Kl + sz;

  qkv_proj<<<dim3(4, 48, 8), 256, 0, stream>>>(x, wq, Qh, Ql, Kh, Kl, V);
  attn_mfma<<<dim3(NBH * 16), 256, 0, stream>>>(Qh, Ql, Kh, Kl, V, rh, rw, out);
}

// Round 4
// 106.475 us; speedup vs baseline: 9.2064x; 1.4459x over previous
//
#include <hip/hip_runtime.h>
#include <hip/hip_bf16.h>
#include <hip/hip_fp16.h>

typedef _Float16 h8 __attribute__((ext_vector_type(8)));
typedef _Float16 h4v __attribute__((ext_vector_type(4)));
typedef unsigned short us8 __attribute__((ext_vector_type(8)));
typedef float f4 __attribute__((ext_vector_type(4)));

#define NH 8
#define DH 64
#define NPIX 1024
#define CIN 64
#define NBH 64
#define QSCALE 512.0f
#define LOSCALE 2048.0f
#define INV_LOSCALE (1.0f / 2048.0f)

__device__ __forceinline__ void gload_lds16(const void* g, void* lds) {
  __builtin_amdgcn_global_load_lds(
      (const __attribute__((address_space(1))) void*)g,
      (__attribute__((address_space(3))) void*)lds, 16, 0, 0);
}

template <int CTRL>
__device__ __forceinline__ float dpp_ror(float x) {
  return __int_as_float(__builtin_amdgcn_update_dpp(
      0, __float_as_int(x), CTRL, 0xF, 0xF, true));
}

// ---------------- QKV projection via compensated fp16 MFMA ----------------
// C[o][p] = sum_c W[o][c] X[c][p] per b.  Block: 128 o x 64 p, K=64.
// Grid (12, 16, 8).  LDS: Wh/Wl [128][64] f16, Xh/Xl [64][64] f16 = 48KB.
__global__ __launch_bounds__(256) void qkv_mfma(
    const float* __restrict__ x, const float* __restrict__ wqkv,
    _Float16* __restrict__ Qh, _Float16* __restrict__ Ql,
    _Float16* __restrict__ Kh, _Float16* __restrict__ Kl,
    _Float16* __restrict__ Vv) {
  __shared__ __align__(16) char QS[49152];
  char* Wh = QS;
  char* Wl = QS + 16384;
  char* Xh = QS + 32768;
  char* Xl = QS + 40960;

  const int tid = threadIdx.x;
  const int lane = tid & 63;
  const int w = tid >> 6;
  const int c = lane & 15;
  const int g = lane >> 4;
  const int o0 = blockIdx.x * 128;
  const int p0 = blockIdx.y * 64;
  const int b = blockIdx.z;

  // ---- stage W tile (hi/lo fp16, chunked+swizzled) ----
  #pragma unroll
  for (int it = 0; it < 4; ++it) {
    int task = tid + it * 256;
    int oct = task & 7, o = task >> 3;
    const f4* wr = (const f4*)(wqkv + (size_t)(o0 + o) * CIN + oct * 8);
    f4 wa = wr[0], wb = wr[1];
    h8 hi, lo;
    #pragma unroll
    for (int e = 0; e < 8; ++e) {
      float v = e < 4 ? wa[e] : wb[e - 4];
      _Float16 h = (_Float16)v;
      hi[e] = h;
      lo[e] = (_Float16)((v - (float)h) * LOSCALE);
    }
    int byo = o * 128 + ((oct ^ (o & 7)) << 4);
    *(h8*)(Wh + byo) = hi;
    *(h8*)(Wl + byo) = lo;
  }
  // ---- stage X tile transposed (hi/lo fp16) ----
  #pragma unroll
  for (int it = 0; it < 16; ++it) {
    int idx = tid + it * 256;
    int p = idx & 63, cc = idx >> 6;
    float v = x[((size_t)b * CIN + cc) * NPIX + p0 + p];
    _Float16 h = (_Float16)v;
    _Float16 l = (_Float16)((v - (float)h) * LOSCALE);
    int byo = p * 128 + (((cc >> 3) ^ (p & 7)) << 4) + (cc & 7) * 2;
    *(_Float16*)(Xh + byo) = h;
    *(_Float16*)(Xl + byo) = l;
  }
  __syncthreads();

  // ---- compute: wave w owns o rows [w*32, w*32+32) x all 64 p ----
  f4 zf = {0.f, 0.f, 0.f, 0.f};
  f4 acc[2][4], cor[2][4];
  #pragma unroll
  for (int oi = 0; oi < 2; ++oi)
    #pragma unroll
    for (int pi = 0; pi < 4; ++pi) { acc[oi][pi] = zf; cor[oi][pi] = zf; }

  const int ob = w * 32;
  #pragma unroll
  for (int kh = 0; kh < 2; ++kh) {
    h8 ah[2], al[2], bh[4], bl[4];
    #pragma unroll
    for (int oi = 0; oi < 2; ++oi) {
      int orow = ob + oi * 16 + c;
      int ch = (((kh * 4 + g) ^ (orow & 7)) << 4);
      ah[oi] = *(const h8*)(Wh + orow * 128 + ch);
      al[oi] = *(const h8*)(Wl + orow * 128 + ch);
    }
    #pragma unroll
    for (int pi = 0; pi < 4; ++pi) {
      int prow = pi * 16 + c;
      int ch = (((kh * 4 + g) ^ (prow & 7)) << 4);
      bh[pi] = *(const h8*)(Xh + prow * 128 + ch);
      bl[pi] = *(const h8*)(Xl + prow * 128 + ch);
    }
    __builtin_amdgcn_s_setprio(1);
    #pragma unroll
    for (int oi = 0; oi < 2; ++oi)
      #pragma unroll
      for (int pi = 0; pi < 4; ++pi) {
        acc[oi][pi] = __builtin_amdgcn_mfma_f32_16x16x32_f16(ah[oi], bh[pi], acc[oi][pi], 0, 0, 0);
        cor[oi][pi] = __builtin_amdgcn_mfma_f32_16x16x32_f16(ah[oi], bl[pi], cor[oi][pi], 0, 0, 0);
        cor[oi][pi] = __builtin_amdgcn_mfma_f32_16x16x32_f16(al[oi], bh[pi], cor[oi][pi], 0, 0, 0);
      }
    __builtin_amdgcn_s_setprio(0);
  }

  // ---- epilogue: compensate, scale, split hi/lo, b64 stores ----
  const int part = o0 >> 9;   // 0=q 1=k 2=v (uniform per block)
  const float scl = part == 0 ? QSCALE : 1.0f;
  _Float16* dsth = part == 0 ? Qh : (part == 1 ? Kh : Vv);
  _Float16* dstl = part == 0 ? Ql : (part == 1 ? Kl : nullptr);
  #pragma unroll
  for (int oi = 0; oi < 2; ++oi)
    #pragma unroll
    for (int pi = 0; pi < 4; ++pi) {
      int o_base = o0 + ob + oi * 16 + 4 * g;
      int h = (o_base >> 6) & 7;
      int d = o_base & 63;
      int p_abs = p0 + pi * 16 + c;
      size_t off = (((size_t)(b * NH + h)) * NPIX + p_abs) * DH + d;
      union { h4v h; unsigned long long u; } uh, ul;
      #pragma unroll
      for (int reg = 0; reg < 4; ++reg) {
        float v = (acc[oi][pi][reg] + cor[oi][pi][reg] * INV_LOSCALE) * scl;
        _Float16 hv = (_Float16)v;
        uh.h[reg] = hv;
        ul.h[reg] = (_Float16)((v - (float)hv) * LOSCALE);
      }
      *(unsigned long long*)(dsth + off) = uh.u;
      if (dstl) *(unsigned long long*)(dstl + off) = ul.u;
    }
}

// ---------------- fused MFMA attention (compensated fp16) ----------------
// Block: one (b,h) x 64 query rows. 4 waves, wave w owns rows w*16..w*16+15.
// 16 j-tiles of 64. LDS chunk layout: 128B rows, byte ^= ((row&7)<<4) swizzle.
__global__ __launch_bounds__(256) void attn_mfma(
    const _Float16* __restrict__ Qh, const _Float16* __restrict__ Ql,
    const _Float16* __restrict__ Kh, const _Float16* __restrict__ Kl,
    const _Float16* __restrict__ V,
    const float* __restrict__ rel_h, const float* __restrict__ rel_w,
    float* __restrict__ out) {
  __shared__ __align__(16) char SMem[40960];
  char* SMkh = SMem;                        // 8KB K-hi chunks
  char* SMkl = SMem + 8192;                 // 8KB K-lo chunks
  char* SMv  = SMem + 16384;                // 8KB V chunks [64 d][8 joct*16B]
  char* SMp  = SMem + 24576;                // 8KB P (2KB/wave)
  _Float16* LH16 = (_Float16*)(SMem + 32768); // [64][64] f16 lh table (8KB)
  float* LWT = (float*)SMem;                // temp f32 [64][64] (over K areas)
  float* OT  = (float*)SMem;                // epilogue reuse (16KB)

  const int tid = threadIdx.x;
  const int lane = tid & 63;
  const int w = tid >> 6;
  const int wu = __builtin_amdgcn_readfirstlane(w);
  const int c = lane & 15;
  const int g = lane >> 4;
  const int bh = blockIdx.x >> 4;
  const int i0 = (blockIdx.x & 15) << 6;

  const _Float16* Qhg = Qh + (size_t)bh * NPIX * DH;
  const _Float16* Qlg = Ql + (size_t)bh * NPIX * DH;
  const _Float16* Khg = Kh + (size_t)bh * NPIX * DH;
  const _Float16* Klg = Kl + (size_t)bh * NPIX * DH;
  const _Float16* Vg  = V  + (size_t)bh * NPIX * DH;

  // Q fragments
  const h8* Qrowh = (const h8*)(Qhg + (size_t)(i0 + w * 16 + c) * DH);
  const h8* Qrowl = (const h8*)(Qlg + (size_t)(i0 + w * 16 + c) * DH);
  h8 qh0 = Qrowh[g], qh1 = Qrowh[4 + g];
  h8 ql0 = Qrowl[g], ql1 = Qrowl[4 + g];

  // per-lane global byte offsets for K gl_lds (pre-swizzled source)
  int s0 = wu * 128 + lane;
  int s1 = s0 + 64;
  int kj0 = s0 >> 3, kc0 = s0 & 7;
  int kj1 = s1 >> 3, kc1 = s1 & 7;
  const int ko0 = kj0 * 128 + ((kc0 ^ (kj0 & 7)) << 4);
  const int ko1 = kj1 * 128 + ((kc1 ^ (kj1 & 7)) << 4);
  char* SMkh_w = SMkh + wu * 2048;
  char* SMkl_w = SMkl + wu * 2048;

  // ---- stage rel tables as fp16 chunks (rows s, swizzled) ----
  #pragma unroll
  for (int it = 0; it < 2; ++it) {
    int task = tid + it * 256;
    int oct = task & 7, s = task >> 3;
    int ss = s < 63 ? s : 62;
    const float* sh = rel_h + (size_t)ss * DH + oct * 8;
    const float* sw = rel_w + (size_t)ss * DH + oct * 8;
    h8 hh, ww;
    #pragma unroll
    for (int e = 0; e < 8; ++e) {
      hh[e] = (_Float16)sh[e];
      ww[e] = (_Float16)sw[e];
    }
    *(h8*)(SMkh + s * 128 + ((oct ^ (s & 7)) << 4)) = hh;
    *(h8*)(SMv + s * 128 + ((oct ^ (s & 7)) << 4)) = ww;
  }
  __syncthreads();

  // ---- lh/lw logit tables via MFMA (with Qlo correction) ----
  f4 zf = {0.f, 0.f, 0.f, 0.f};
  f4 lhC[4], lwC[4], lhCc[4], lwCc[4];
  #pragma unroll
  for (int cg = 0; cg < 4; ++cg) { lhC[cg] = zf; lwC[cg] = zf; lhCc[cg] = zf; lwCc[cg] = zf; }
  #pragma unroll
  for (int kh = 0; kh < 2; ++kh) {
    h8 a  = kh == 0 ? qh0 : qh1;
    h8 al = kh == 0 ? ql0 : ql1;
    #pragma unroll
    for (int cg = 0; cg < 4; ++cg) {
      int s = cg * 16 + c;
      h8 rb = *(const h8*)(SMkh + s * 128 + (((kh * 4 + g) ^ (s & 7)) << 4));
      lhC[cg]  = __builtin_amdgcn_mfma_f32_16x16x32_f16(a,  rb, lhC[cg], 0, 0, 0);
      lhCc[cg] = __builtin_amdgcn_mfma_f32_16x16x32_f16(al, rb, lhCc[cg], 0, 0, 0);
      h8 wb = *(const h8*)(SMv + s * 128 + (((kh * 4 + g) ^ (s & 7)) << 4));
      lwC[cg]  = __builtin_amdgcn_mfma_f32_16x16x32_f16(a,  wb, lwC[cg], 0, 0, 0);
      lwCc[cg] = __builtin_amdgcn_mfma_f32_16x16x32_f16(al, wb, lwCc[cg], 0, 0, 0);
    }
  }
  #pragma unroll
  for (int cg = 0; cg < 4; ++cg)
    #pragma unroll
    for (int reg = 0; reg < 4; ++reg)
      LH16[(w * 16 + 4 * g + reg) * 64 + cg * 16 + c] =
          (_Float16)(lhC[cg][reg] + lhCc[cg][reg] * INV_LOSCALE);
  __syncthreads();   // rel chunks fully consumed
  #pragma unroll
  for (int cg = 0; cg < 4; ++cg)
    #pragma unroll
    for (int reg = 0; reg < 4; ++reg)
      LWT[(w * 16 + 4 * g + reg) * 64 + cg * 16 + c] =
          lwC[cg][reg] + lwCc[cg][reg] * INV_LOSCALE;

  // lw values needed forever: row (4g+reg), xj in {c, 16+c}
  float lwreg[4][2];
  #pragma unroll
  for (int reg = 0; reg < 4; ++reg) {
    int r = w * 16 + 4 * g + reg;
    int xi = r & 31;
    #pragma unroll
    for (int par = 0; par < 2; ++par)
      lwreg[reg][par] = LWT[r * 64 + 31 + par * 16 + c - xi];
  }

  const int yi = (i0 + w * 16) >> 5;
  float m_s[4], l_s[4];
  f4 o_[4];
  #pragma unroll
  for (int reg = 0; reg < 4; ++reg) { m_s[reg] = -1e30f; l_s[reg] = 0.f; }
  #pragma unroll
  for (int cg = 0; cg < 4; ++cg) o_[cg] = zf;

  #pragma unroll 1
  for (int t = 0; t < 16; ++t) {
    const int j0 = t << 6;
    __syncthreads();   // prev tile consumed (and LWT consumed at t=0)

    // stage K hi/lo via global_load_lds (pre-swizzled global source)
    {
      const char* kg  = (const char*)Khg + (size_t)j0 * 128;
      const char* klg = (const char*)Klg + (size_t)j0 * 128;
      gload_lds16(kg + ko0, SMkh_w);
      gload_lds16(kg + ko1, SMkh_w + 1024);
      gload_lds16(klg + ko0, SMkl_w);
      gload_lds16(klg + ko1, SMkl_w + 1024);
    }
    // stage V transposed: j-pairs packed as u32 column writes
    {
      int jp = tid & 31, dd = tid >> 5;
      const h8* vr = (const h8*)(Vg + (size_t)(j0 + 2 * jp) * DH);
      h8 v0 = vr[dd];
      h8 v1 = vr[8 + dd];
      us8 u0 = *(const us8*)&v0;
      us8 u1 = *(const us8*)&v1;
      #pragma unroll
      for (int e = 0; e < 8; ++e) {
        int d = dd * 8 + e;
        unsigned int val = (unsigned int)u0[e] | ((unsigned int)u1[e] << 16);
        *(unsigned int*)(SMv + d * 128 + (((jp >> 2) ^ (d & 7)) << 4) + (jp & 3) * 4) = val;
      }
    }
    __syncthreads();

    // QK^T -> S (row = 4g+reg, col j = 16cg+c), compensated
    f4 s_[4], sc_[4];
    #pragma unroll
    for (int cg = 0; cg < 4; ++cg) { s_[cg] = zf; sc_[cg] = zf; }
    #pragma unroll
    for (int kh = 0; kh < 2; ++kh) {
      h8 a  = kh == 0 ? qh0 : qh1;
      h8 al = kh == 0 ? ql0 : ql1;
      #pragma unroll
      for (int cg = 0; cg < 4; ++cg) {
        int j = cg * 16 + c;
        h8 kbh = *(const h8*)(SMkh + j * 128 + (((kh * 4 + g) ^ (j & 7)) << 4));
        h8 kbl = *(const h8*)(SMkl + j * 128 + (((kh * 4 + g) ^ (j & 7)) << 4));
        __builtin_amdgcn_s_setprio(1);
        s_[cg]  = __builtin_amdgcn_mfma_f32_16x16x32_f16(a,  kbh, s_[cg], 0, 0, 0);
        sc_[cg] = __builtin_amdgcn_mfma_f32_16x16x32_f16(al, kbh, sc_[cg], 0, 0, 0);
        sc_[cg] = __builtin_amdgcn_mfma_f32_16x16x32_f16(a,  kbl, sc_[cg], 0, 0, 0);
        __builtin_amdgcn_s_setprio(0);
      }
    }

    // bias: + correction + lh[row][31 + yj - yi] + lw[row][31 + xj - xi]
    float lhv[4][2];
    #pragma unroll
    for (int reg = 0; reg < 4; ++reg) {
      int r = w * 16 + 4 * g + reg;
      int base = 31 + 2 * t - yi;
      lhv[reg][0] = (float)LH16[r * 64 + base];
      lhv[reg][1] = (float)LH16[r * 64 + base + 1];
    }
    #pragma unroll
    for (int cg = 0; cg < 4; ++cg)
      #pragma unroll
      for (int reg = 0; reg < 4; ++reg)
        s_[cg][reg] += sc_[cg][reg] * INV_LOSCALE + lwreg[reg][cg & 1] + lhv[reg][cg >> 1];

    // online softmax: 16-lane row reduce via DPP row_ror (off LDS pipe)
    float p_[4][4];
    float corr[4];
    #pragma unroll
    for (int reg = 0; reg < 4; ++reg) {
      float tm = fmaxf(fmaxf(s_[0][reg], s_[1][reg]), fmaxf(s_[2][reg], s_[3][reg]));
      tm = fmaxf(tm, dpp_ror<0x121>(tm));
      tm = fmaxf(tm, dpp_ror<0x122>(tm));
      tm = fmaxf(tm, dpp_ror<0x124>(tm));
      tm = fmaxf(tm, dpp_ror<0x128>(tm));
      float mn = fmaxf(m_s[reg], tm);
      corr[reg] = __expf(m_s[reg] - mn);
      m_s[reg] = mn;
      float ps = 0.f;
      #pragma unroll
      for (int cg = 0; cg < 4; ++cg) {
        float pv = __expf(s_[cg][reg] - mn);
        p_[cg][reg] = pv;
        ps += pv;
      }
      ps += dpp_ror<0x121>(ps);
      ps += dpp_ror<0x122>(ps);
      ps += dpp_ror<0x124>(ps);
      ps += dpp_ror<0x128>(ps);
      l_s[reg] = l_s[reg] * corr[reg] + ps;
    }
    #pragma unroll
    for (int cg = 0; cg < 4; ++cg)
      #pragma unroll
      for (int reg = 0; reg < 4; ++reg)
        o_[cg][reg] *= corr[reg];

    // write P (fp16) to per-wave LDS
    #pragma unroll
    for (int cg = 0; cg < 4; ++cg)
      #pragma unroll
      for (int reg = 0; reg < 4; ++reg) {
        int r = 4 * g + reg;
        int j = cg * 16 + c;
        *(_Float16*)(SMp + w * 2048 + r * 128 + (((j >> 3) ^ (r & 7)) << 4) + (j & 7) * 2)
            = (_Float16)p_[cg][reg];
      }
    __builtin_amdgcn_wave_barrier();

    // PV: A = P, B = V chunks
    #pragma unroll
    for (int kh = 0; kh < 2; ++kh) {
      h8 pa = *(const h8*)(SMp + w * 2048 + c * 128 + (((kh * 4 + g) ^ (c & 7)) << 4));
      __builtin_amdgcn_s_setprio(1);
      #pragma unroll
      for (int cgd = 0; cgd < 4; ++cgd) {
        int d = cgd * 16 + c;
        h8 vb = *(const h8*)(SMv + d * 128 + (((kh * 4 + g) ^ (d & 7)) << 4));
        o_[cgd] = __builtin_amdgcn_mfma_f32_16x16x32_f16(pa, vb, o_[cgd], 0, 0, 0);
      }
      __builtin_amdgcn_s_setprio(0);
    }
  }

  // ---- epilogue: normalize, transpose via LDS (reuse K areas), store ----
  __syncthreads();
  #pragma unroll
  for (int cgd = 0; cgd < 4; ++cgd)
    #pragma unroll
    for (int reg = 0; reg < 4; ++reg) {
      int d = cgd * 16 + c;
      int r = w * 16 + 4 * g + reg;
      OT[d * 64 + (r ^ ((d & 7) << 3))] = o_[cgd][reg] / l_s[reg];
    }
  __syncthreads();
  #pragma unroll
  for (int it = 0; it < 4; ++it) {
    int task = tid + it * 256;
    int rq = task & 15, d = task >> 4;
    f4 vv = *(const f4*)&OT[d * 64 + ((rq * 4) ^ ((d & 7) << 3))];
    *(f4*)(out + (((size_t)bh * 64 + d) << 10) + i0 + rq * 4) = vv;
  }
}

extern "C" void kernel_launch(void* const* d_in, const int* in_sizes, int n_in,
                              void* d_out, int out_size, void* d_ws, size_t ws_size,
                              hipStream_t stream) {
  const float* x  = (const float*)d_in[0];
  const float* wq = (const float*)d_in[1];
  const float* rh = (const float*)d_in[2];
  const float* rw = (const float*)d_in[3];
  float* out = (float*)d_out;

  const size_t sz = (size_t)NBH * NPIX * DH;   // 4M halves = 8MB each
  _Float16* Qh = (_Float16*)d_ws;
  _Float16* Ql = Qh + sz;
  _Float16* Kh = Ql + sz;
  _Float16* Kl = Kh + sz;
  _Float16* V  = Kl + sz;

  qkv_mfma<<<dim3(12, 16, 8), 256, 0, stream>>>(x, wq, Qh, Ql, Kh, Kl, V);
  attn_mfma<<<dim3(NBH * 16), 256, 0, stream>>>(Qh, Ql, Kh, Kl, V, rh, rw, out);
}

// Round 5
// 90.821 us; speedup vs baseline: 10.7932x; 1.1724x over previous
//
#include <hip/hip_runtime.h>
#include <hip/hip_bf16.h>
#include <hip/hip_fp16.h>

typedef _Float16 h8 __attribute__((ext_vector_type(8)));
typedef _Float16 h4v __attribute__((ext_vector_type(4)));
typedef unsigned short us8 __attribute__((ext_vector_type(8)));
typedef float f4 __attribute__((ext_vector_type(4)));

#define NH 8
#define DH 64
#define NPIX 1024
#define CIN 64
#define NBH 64
#define QSCALE 512.0f
#define LOSCALE 2048.0f
#define INV_LOSCALE (1.0f / 2048.0f)

__device__ __forceinline__ void gload_lds16(const void* g, void* lds) {
  __builtin_amdgcn_global_load_lds(
      (const __attribute__((address_space(1))) void*)g,
      (__attribute__((address_space(3))) void*)lds, 16, 0, 0);
}

template <int CTRL>
__device__ __forceinline__ float dpp_ror(float x) {
  return __int_as_float(__builtin_amdgcn_update_dpp(
      0, __float_as_int(x), CTRL, 0xF, 0xF, true));
}

// ---------------- QKV projection via compensated fp16 MFMA ----------------
__global__ __launch_bounds__(256) void qkv_mfma(
    const float* __restrict__ x, const float* __restrict__ wqkv,
    _Float16* __restrict__ Qh, _Float16* __restrict__ Ql,
    _Float16* __restrict__ Kh, _Float16* __restrict__ Kl,
    _Float16* __restrict__ Vv) {
  __shared__ __align__(16) char QS[49152];
  char* Wh = QS;
  char* Wl = QS + 16384;
  char* Xh = QS + 32768;
  char* Xl = QS + 40960;

  const int tid = threadIdx.x;
  const int lane = tid & 63;
  const int w = tid >> 6;
  const int c = lane & 15;
  const int g = lane >> 4;
  const int o0 = blockIdx.x * 128;
  const int p0 = blockIdx.y * 64;
  const int b = blockIdx.z;

  #pragma unroll
  for (int it = 0; it < 4; ++it) {
    int task = tid + it * 256;
    int oct = task & 7, o = task >> 3;
    const f4* wr = (const f4*)(wqkv + (size_t)(o0 + o) * CIN + oct * 8);
    f4 wa = wr[0], wb = wr[1];
    h8 hi, lo;
    #pragma unroll
    for (int e = 0; e < 8; ++e) {
      float v = e < 4 ? wa[e] : wb[e - 4];
      _Float16 h = (_Float16)v;
      hi[e] = h;
      lo[e] = (_Float16)((v - (float)h) * LOSCALE);
    }
    int byo = o * 128 + ((oct ^ (o & 7)) << 4);
    *(h8*)(Wh + byo) = hi;
    *(h8*)(Wl + byo) = lo;
  }
  #pragma unroll
  for (int it = 0; it < 16; ++it) {
    int idx = tid + it * 256;
    int p = idx & 63, cc = idx >> 6;
    float v = x[((size_t)b * CIN + cc) * NPIX + p0 + p];
    _Float16 h = (_Float16)v;
    _Float16 l = (_Float16)((v - (float)h) * LOSCALE);
    int byo = p * 128 + (((cc >> 3) ^ (p & 7)) << 4) + (cc & 7) * 2;
    *(_Float16*)(Xh + byo) = h;
    *(_Float16*)(Xl + byo) = l;
  }
  __syncthreads();

  f4 zf = {0.f, 0.f, 0.f, 0.f};
  f4 acc[2][4], cor[2][4];
  #pragma unroll
  for (int oi = 0; oi < 2; ++oi)
    #pragma unroll
    for (int pi = 0; pi < 4; ++pi) { acc[oi][pi] = zf; cor[oi][pi] = zf; }

  const int ob = w * 32;
  #pragma unroll
  for (int kh = 0; kh < 2; ++kh) {
    h8 ah[2], al[2], bh[4], bl[4];
    #pragma unroll
    for (int oi = 0; oi < 2; ++oi) {
      int orow = ob + oi * 16 + c;
      int ch = (((kh * 4 + g) ^ (orow & 7)) << 4);
      ah[oi] = *(const h8*)(Wh + orow * 128 + ch);
      al[oi] = *(const h8*)(Wl + orow * 128 + ch);
    }
    #pragma unroll
    for (int pi = 0; pi < 4; ++pi) {
      int prow = pi * 16 + c;
      int ch = (((kh * 4 + g) ^ (prow & 7)) << 4);
      bh[pi] = *(const h8*)(Xh + prow * 128 + ch);
      bl[pi] = *(const h8*)(Xl + prow * 128 + ch);
    }
    __builtin_amdgcn_s_setprio(1);
    #pragma unroll
    for (int oi = 0; oi < 2; ++oi)
      #pragma unroll
      for (int pi = 0; pi < 4; ++pi) {
        acc[oi][pi] = __builtin_amdgcn_mfma_f32_16x16x32_f16(ah[oi], bh[pi], acc[oi][pi], 0, 0, 0);
        cor[oi][pi] = __builtin_amdgcn_mfma_f32_16x16x32_f16(ah[oi], bl[pi], cor[oi][pi], 0, 0, 0);
        cor[oi][pi] = __builtin_amdgcn_mfma_f32_16x16x32_f16(al[oi], bh[pi], cor[oi][pi], 0, 0, 0);
      }
    __builtin_amdgcn_s_setprio(0);
  }

  const int part = o0 >> 9;
  const float scl = part == 0 ? QSCALE : 1.0f;
  _Float16* dsth = part == 0 ? Qh : (part == 1 ? Kh : Vv);
  _Float16* dstl = part == 0 ? Ql : (part == 1 ? Kl : nullptr);
  #pragma unroll
  for (int oi = 0; oi < 2; ++oi)
    #pragma unroll
    for (int pi = 0; pi < 4; ++pi) {
      int o_base = o0 + ob + oi * 16 + 4 * g;
      int h = (o_base >> 6) & 7;
      int d = o_base & 63;
      int p_abs = p0 + pi * 16 + c;
      size_t off = (((size_t)(b * NH + h)) * NPIX + p_abs) * DH + d;
      union { h4v h; unsigned long long u; } uh, ul;
      #pragma unroll
      for (int reg = 0; reg < 4; ++reg) {
        float v = (acc[oi][pi][reg] + cor[oi][pi][reg] * INV_LOSCALE) * scl;
        _Float16 hv = (_Float16)v;
        uh.h[reg] = hv;
        ul.h[reg] = (_Float16)((v - (float)hv) * LOSCALE);
      }
      *(unsigned long long*)(dsth + off) = uh.u;
      if (dstl) *(unsigned long long*)(dstl + off) = ul.u;
    }
}

// ---------------- fused MFMA attention (compensated fp16, async 2-phase) ----
// Block: one (b,h) x 128 query rows. 4 waves; wave w owns rows w*32..w*32+31
// (two 16-row A-fragment sets). 16 j-tiles of 64, double-buffered K/V.
__global__ __launch_bounds__(256, 2) void attn_mfma(
    const _Float16* __restrict__ Qh, const _Float16* __restrict__ Ql,
    const _Float16* __restrict__ Kh, const _Float16* __restrict__ Kl,
    const _Float16* __restrict__ V,
    const float* __restrict__ rel_h, const float* __restrict__ rel_w,
    float* __restrict__ out) {
  // +0      Khi[2]   2x8KB   (prologue: rel_h; epilogue: OT low half)
  // +16384  Klo[2]   2x8KB   (epilogue: OT high half)
  // +32768  V[2]     2x8KB   (prologue: rel_w)
  // +49152  P / LWT16 16KB
  // +65536  LH16      16KB
  __shared__ __align__(16) char SMem[81920];
  char* SMp = SMem + 49152;
  _Float16* LWT16 = (_Float16*)SMp;
  _Float16* LH16 = (_Float16*)(SMem + 65536);
  float* OT = (float*)SMem;

  const int tid = threadIdx.x;
  const int lane = tid & 63;
  const int w = tid >> 6;
  const int wu = __builtin_amdgcn_readfirstlane(w);
  const int c = lane & 15;
  const int g = lane >> 4;
  const int bx = blockIdx.x;
  const int bh = ((bx & 7) << 3) | ((bx >> 3) & 7);   // XCD-local bh groups
  const int i0 = (bx >> 6) << 7;

  const _Float16* Qhg = Qh + (size_t)bh * NPIX * DH;
  const _Float16* Qlg = Ql + (size_t)bh * NPIX * DH;
  const _Float16* Khg = Kh + (size_t)bh * NPIX * DH;
  const _Float16* Klg = Kl + (size_t)bh * NPIX * DH;
  const _Float16* Vg  = V  + (size_t)bh * NPIX * DH;

  // Q fragments: 2 rowsets x (2 kh) x hi/lo
  const h8* Qr0h = (const h8*)(Qhg + (size_t)(i0 + w * 32 + c) * DH);
  const h8* Qr0l = (const h8*)(Qlg + (size_t)(i0 + w * 32 + c) * DH);
  const h8* Qr1h = (const h8*)(Qhg + (size_t)(i0 + w * 32 + 16 + c) * DH);
  const h8* Qr1l = (const h8*)(Qlg + (size_t)(i0 + w * 32 + 16 + c) * DH);
  h8 q0h[2] = {Qr0h[g], Qr0h[4 + g]};
  h8 q0l[2] = {Qr0l[g], Qr0l[4 + g]};
  h8 q1h[2] = {Qr1h[g], Qr1h[4 + g]};
  h8 q1l[2] = {Qr1l[g], Qr1l[4 + g]};

  // K staging: pre-swizzled per-lane global byte offsets (dest is linear)
  const int s0 = wu * 128 + lane;
  const int s1 = s0 + 64;
  const int ko0 = (s0 >> 3) * 128 + (((s0 & 7) ^ ((s0 >> 3) & 7)) << 4);
  const int ko1 = (s1 >> 3) * 128 + (((s1 & 7) ^ ((s1 >> 3) & 7)) << 4);

  // ---- stage rel tables as fp16 chunks ----
  #pragma unroll
  for (int it = 0; it < 2; ++it) {
    int task = tid + it * 256;
    int oct = task & 7, s = task >> 3;
    int ss = s < 63 ? s : 62;
    const float* sh = rel_h + (size_t)ss * DH + oct * 8;
    const float* sw = rel_w + (size_t)ss * DH + oct * 8;
    h8 hh, ww;
    #pragma unroll
    for (int e = 0; e < 8; ++e) {
      hh[e] = (_Float16)sh[e];
      ww[e] = (_Float16)sw[e];
    }
    int byo = s * 128 + ((oct ^ (s & 7)) << 4);
    *(h8*)(SMem + byo) = hh;           // rel_h in Khi0 area
    *(h8*)(SMem + 32768 + byo) = ww;   // rel_w in V0 area
  }
  __syncthreads();

  // ---- lh/lw logit tables via MFMA (with Qlo correction), fp16 out ----
  f4 zf = {0.f, 0.f, 0.f, 0.f};
  #pragma unroll
  for (int rs = 0; rs < 2; ++rs) {
    f4 lhC[4], lwC[4], lhCc[4], lwCc[4];
    #pragma unroll
    for (int cg = 0; cg < 4; ++cg) { lhC[cg] = zf; lwC[cg] = zf; lhCc[cg] = zf; lwCc[cg] = zf; }
    #pragma unroll
    for (int kh = 0; kh < 2; ++kh) {
      h8 a  = rs ? q1h[kh] : q0h[kh];
      h8 al = rs ? q1l[kh] : q0l[kh];
      #pragma unroll
      for (int cg = 0; cg < 4; ++cg) {
        int s = cg * 16 + c;
        int chb = s * 128 + (((kh * 4 + g) ^ (s & 7)) << 4);
        h8 rb = *(const h8*)(SMem + chb);
        h8 wb = *(const h8*)(SMem + 32768 + chb);
        lhC[cg]  = __builtin_amdgcn_mfma_f32_16x16x32_f16(a,  rb, lhC[cg], 0, 0, 0);
        lhCc[cg] = __builtin_amdgcn_mfma_f32_16x16x32_f16(al, rb, lhCc[cg], 0, 0, 0);
        lwC[cg]  = __builtin_amdgcn_mfma_f32_16x16x32_f16(a,  wb, lwC[cg], 0, 0, 0);
        lwCc[cg] = __builtin_amdgcn_mfma_f32_16x16x32_f16(al, wb, lwCc[cg], 0, 0, 0);
      }
    }
    #pragma unroll
    for (int cg = 0; cg < 4; ++cg)
      #pragma unroll
      for (int reg = 0; reg < 4; ++reg) {
        int r = w * 32 + rs * 16 + 4 * g + reg;
        int col = cg * 16 + c;
        LH16[r * 64 + (col ^ (((r >> 2) & 3) << 4))] =
            (_Float16)(lhC[cg][reg] + lhCc[cg][reg] * INV_LOSCALE);
        LWT16[r * 64 + col] =
            (_Float16)(lwC[cg][reg] + lwCc[cg][reg] * INV_LOSCALE);
      }
  }
  __syncthreads();   // rel areas consumed; LH/LWT visible

  // lw values kept in registers (reads from own wave's P region only)
  float lw0[4][2], lw1[4][2];
  #pragma unroll
  for (int reg = 0; reg < 4; ++reg) {
    int xi0 = 4 * g + reg;
    int r0 = w * 32 + xi0;
    #pragma unroll
    for (int par = 0; par < 2; ++par) {
      lw0[reg][par] = (float)LWT16[r0 * 64 + 31 + par * 16 + c - xi0];
      lw1[reg][par] = (float)LWT16[(r0 + 16) * 64 + 31 + par * 16 + c - (xi0 + 16)];
    }
  }

  // ---- stage tile 0 into buffer 0 ----
  {
    gload_lds16((const char*)Khg + ko0, SMem + wu * 2048);
    gload_lds16((const char*)Khg + ko1, SMem + wu * 2048 + 1024);
    gload_lds16((const char*)Klg + ko0, SMem + 16384 + wu * 2048);
    gload_lds16((const char*)Klg + ko1, SMem + 16384 + wu * 2048 + 1024);
    int jp = tid & 31, dd = tid >> 5;
    const h8* vr = (const h8*)(Vg + (size_t)(2 * jp) * DH);
    h8 v0 = vr[dd], v1 = vr[8 + dd];
    us8 u0 = *(const us8*)&v0, u1 = *(const us8*)&v1;
    #pragma unroll
    for (int e = 0; e < 8; ++e) {
      int d = dd * 8 + e;
      unsigned int val = (unsigned int)u0[e] | ((unsigned int)u1[e] << 16);
      *(unsigned int*)(SMem + 32768 + d * 128 + (((jp >> 2) ^ (d & 7)) << 4) + (jp & 3) * 4) = val;
    }
  }
  __syncthreads();

  const int yi = (i0 >> 5) + w;   // uniform per wave
  float m0[4], l0[4], m1[4], l1[4];
  f4 o0_[4], o1_[4];
  #pragma unroll
  for (int reg = 0; reg < 4; ++reg) { m0[reg] = -1e30f; l0[reg] = 0.f; m1[reg] = -1e30f; l1[reg] = 0.f; }
  #pragma unroll
  for (int cg = 0; cg < 4; ++cg) { o0_[cg] = zf; o1_[cg] = zf; }

  int cur = 0;
  #pragma unroll 1
  for (int t = 0; t < 16; ++t) {
    char* Kc  = SMem + cur * 8192;
    char* KLc = SMem + 16384 + cur * 8192;
    char* Vc  = SMem + 32768 + cur * 8192;
    const int nxt = cur ^ 1;
    const bool pre = t < 15;
    const int jp = tid & 31, dd = tid >> 5;
    h8 v0 = {}, v1 = {};
    if (pre) {   // issue next-tile loads early; latency hides under compute
      const char* kg  = (const char*)Khg + (size_t)(t + 1) * 8192;
      const char* klg = (const char*)Klg + (size_t)(t + 1) * 8192;
      char* Kn  = SMem + nxt * 8192;
      char* KLn = SMem + 16384 + nxt * 8192;
      gload_lds16(kg + ko0, Kn + wu * 2048);
      gload_lds16(kg + ko1, Kn + wu * 2048 + 1024);
      gload_lds16(klg + ko0, KLn + wu * 2048);
      gload_lds16(klg + ko1, KLn + wu * 2048 + 1024);
      const h8* vr = (const h8*)(Vg + (size_t)((t + 1) * 64 + 2 * jp) * DH);
      v0 = vr[dd];
      v1 = vr[8 + dd];
    }

    // ---- QK^T both rowsets (K fragments read once, serve 32 rows) ----
    f4 s0_[4], sc0_[4], s1_[4], sc1_[4];
    #pragma unroll
    for (int cg = 0; cg < 4; ++cg) { s0_[cg] = zf; sc0_[cg] = zf; s1_[cg] = zf; sc1_[cg] = zf; }
    #pragma unroll
    for (int kh = 0; kh < 2; ++kh) {
      h8 a0 = q0h[kh], a0l = q0l[kh], a1 = q1h[kh], a1l = q1l[kh];
      #pragma unroll
      for (int cg = 0; cg < 4; ++cg) {
        int j = cg * 16 + c;
        int chb = j * 128 + (((kh * 4 + g) ^ (j & 7)) << 4);
        h8 kbh = *(const h8*)(Kc + chb);
        h8 kbl = *(const h8*)(KLc + chb);
        __builtin_amdgcn_s_setprio(1);
        s0_[cg]  = __builtin_amdgcn_mfma_f32_16x16x32_f16(a0,  kbh, s0_[cg], 0, 0, 0);
        sc0_[cg] = __builtin_amdgcn_mfma_f32_16x16x32_f16(a0l, kbh, sc0_[cg], 0, 0, 0);
        sc0_[cg] = __builtin_amdgcn_mfma_f32_16x16x32_f16(a0,  kbl, sc0_[cg], 0, 0, 0);
        s1_[cg]  = __builtin_amdgcn_mfma_f32_16x16x32_f16(a1,  kbh, s1_[cg], 0, 0, 0);
        sc1_[cg] = __builtin_amdgcn_mfma_f32_16x16x32_f16(a1l, kbh, sc1_[cg], 0, 0, 0);
        sc1_[cg] = __builtin_amdgcn_mfma_f32_16x16x32_f16(a1,  kbl, sc1_[cg], 0, 0, 0);
        __builtin_amdgcn_s_setprio(0);
      }
    }

    const int lhb = 31 + 2 * t - yi;
    auto finish = [&](f4* s_, f4* sc_, float (*lw)[2], float* m_s, float* l_s,
                      f4* o_, int rs) {
      float lhv[4][2];
      #pragma unroll
      for (int reg = 0; reg < 4; ++reg) {
        int r = w * 32 + rs * 16 + 4 * g + reg;
        int msk = ((r >> 2) & 3) << 4;
        lhv[reg][0] = (float)LH16[r * 64 + (lhb ^ msk)];
        lhv[reg][1] = (float)LH16[r * 64 + ((lhb + 1) ^ msk)];
      }
      #pragma unroll
      for (int cg = 0; cg < 4; ++cg)
        #pragma unroll
        for (int reg = 0; reg < 4; ++reg)
          s_[cg][reg] += sc_[cg][reg] * INV_LOSCALE + lw[reg][cg & 1] + lhv[reg][cg >> 1];
      #pragma unroll
      for (int reg = 0; reg < 4; ++reg) {
        float tm = fmaxf(fmaxf(s_[0][reg], s_[1][reg]), fmaxf(s_[2][reg], s_[3][reg]));
        tm = fmaxf(tm, dpp_ror<0x121>(tm));
        tm = fmaxf(tm, dpp_ror<0x122>(tm));
        tm = fmaxf(tm, dpp_ror<0x124>(tm));
        tm = fmaxf(tm, dpp_ror<0x128>(tm));
        float mn = fmaxf(m_s[reg], tm);
        float corr = __expf(m_s[reg] - mn);
        m_s[reg] = mn;
        float ps = 0.f;
        float pv[4];
        #pragma unroll
        for (int cg = 0; cg < 4; ++cg) { pv[cg] = __expf(s_[cg][reg] - mn); ps += pv[cg]; }
        ps += dpp_ror<0x121>(ps);
        ps += dpp_ror<0x122>(ps);
        ps += dpp_ror<0x124>(ps);
        ps += dpp_ror<0x128>(ps);
        l_s[reg] = l_s[reg] * corr + ps;
        #pragma unroll
        for (int cg = 0; cg < 4; ++cg) o_[cg][reg] *= corr;
        int r2 = rs * 16 + 4 * g + reg;
        #pragma unroll
        for (int cg = 0; cg < 4; ++cg) {
          int j = cg * 16 + c;
          *(_Float16*)(SMp + w * 4096 + r2 * 128 + (((j >> 3) ^ (r2 & 7)) << 4) + (j & 7) * 2)
              = (_Float16)pv[cg];
        }
      }
    };
    finish(s0_, sc0_, lw0, m0, l0, o0_, 0);
    finish(s1_, sc1_, lw1, m1, l1, o1_, 1);
    __builtin_amdgcn_wave_barrier();

    // ---- PV ----
    #pragma unroll
    for (int kh = 0; kh < 2; ++kh) {
      int oc = kh * 4 + g;
      h8 pa0 = *(const h8*)(SMp + w * 4096 + c * 128 + ((oc ^ (c & 7)) << 4));
      h8 pa1 = *(const h8*)(SMp + w * 4096 + (16 + c) * 128 + ((oc ^ (c & 7)) << 4));
      __builtin_amdgcn_s_setprio(1);
      #pragma unroll
      for (int cgd = 0; cgd < 4; ++cgd) {
        int d = cgd * 16 + c;
        h8 vb = *(const h8*)(Vc + d * 128 + ((oc ^ (d & 7)) << 4));
        o0_[cgd] = __builtin_amdgcn_mfma_f32_16x16x32_f16(pa0, vb, o0_[cgd], 0, 0, 0);
        o1_[cgd] = __builtin_amdgcn_mfma_f32_16x16x32_f16(pa1, vb, o1_[cgd], 0, 0, 0);
      }
      __builtin_amdgcn_s_setprio(0);
    }

    if (pre) {   // T14: write prefetched V after compute
      us8 u0 = *(const us8*)&v0, u1 = *(const us8*)&v1;
      char* Vn = SMem + 32768 + nxt * 8192;
      #pragma unroll
      for (int e = 0; e < 8; ++e) {
        int d = dd * 8 + e;
        unsigned int val = (unsigned int)u0[e] | ((unsigned int)u1[e] << 16);
        *(unsigned int*)(Vn + d * 128 + (((jp >> 2) ^ (d & 7)) << 4) + (jp & 3) * 4) = val;
      }
    }
    __syncthreads();
    cur = nxt;
  }

  // ---- epilogue: normalize, transpose via OT (over K buffers), store ----
  #pragma unroll
  for (int cgd = 0; cgd < 4; ++cgd)
    #pragma unroll
    for (int reg = 0; reg < 4; ++reg) {
      int d = cgd * 16 + c;
      int sw = (d & 7) << 3;
      int r0 = w * 32 + 4 * g + reg;
      OT[d * 128 + (r0 ^ sw)] = o0_[cgd][reg] / l0[reg];
      OT[d * 128 + ((r0 + 16) ^ sw)] = o1_[cgd][reg] / l1[reg];
    }
  __syncthreads();
  #pragma unroll
  for (int it = 0; it < 8; ++it) {
    int task = tid + it * 256;
    int rq = task & 31, d = task >> 5;
    f4 vv = *(const f4*)&OT[d * 128 + ((rq * 4) ^ ((d & 7) << 3))];
    *(f4*)(out + (((size_t)bh * 64 + d) << 10) + i0 + rq * 4) = vv;
  }
}

extern "C" void kernel_launch(void* const* d_in, const int* in_sizes, int n_in,
                              void* d_out, int out_size, void* d_ws, size_t ws_size,
                              hipStream_t stream) {
  const float* x  = (const float*)d_in[0];
  const float* wq = (const float*)d_in[1];
  const float* rh = (const float*)d_in[2];
  const float* rw = (const float*)d_in[3];
  float* out = (float*)d_out;

  const size_t sz = (size_t)NBH * NPIX * DH;   // 4M halves = 8MB each
  _Float16* Qh = (_Float16*)d_ws;
  _Float16* Ql = Qh + sz;
  _Float16* Kh = Ql + sz;
  _Float16* Kl = Kh + sz;
  _Float16* V  = Kl + sz;

  qkv_mfma<<<dim3(12, 16, 8), 256, 0, stream>>>(x, wq, Qh, Ql, Kh, Kl, V);
  attn_mfma<<<dim3(512), 256, 0, stream>>>(Qh, Ql, Kh, Kl, V, rh, rw, out);
}

// Round 6
// 88.596 us; speedup vs baseline: 11.0643x; 1.0251x over previous
//
#include <hip/hip_runtime.h>
#include <hip/hip_bf16.h>
#include <hip/hip_fp16.h>

typedef _Float16 h8 __attribute__((ext_vector_type(8)));
typedef unsigned short us8 __attribute__((ext_vector_type(8)));
typedef float f4 __attribute__((ext_vector_type(4)));

#define NH 8
#define DH 64
#define NPIX 1024
#define CIN 64
#define NBH 64
// 512 (ref scale) * log2(e): logits come out in base-2 units
#define QSCALE (512.0f * 1.44269504f)
#define LOSCALE 2048.0f
#define INV_LOSCALE (1.0f / 2048.0f)
#define DTHR 12.0f

__device__ __forceinline__ void gload_lds16(const void* g, void* lds) {
  __builtin_amdgcn_global_load_lds(
      (const __attribute__((address_space(1))) void*)g,
      (__attribute__((address_space(3))) void*)lds, 16, 0, 0);
}

template <int CTRL>
__device__ __forceinline__ float dpp_ror(float x) {
  return __int_as_float(__builtin_amdgcn_update_dpp(
      0, __float_as_int(x), CTRL, 0xF, 0xF, true));
}

__device__ __forceinline__ float fexp2(float x) {
#if __has_builtin(__builtin_amdgcn_exp2f)
  return __builtin_amdgcn_exp2f(x);
#else
  return exp2f(x);
#endif
}

// ---------------- QKV projection via compensated fp16 MFMA ----------------
__global__ __launch_bounds__(256) void qkv_mfma(
    const float* __restrict__ x, const float* __restrict__ wqkv,
    _Float16* __restrict__ Qh, _Float16* __restrict__ Ql,
    _Float16* __restrict__ Kh, _Float16* __restrict__ Kl,
    _Float16* __restrict__ Vv) {
  __shared__ __align__(16) char QS[49152];
  char* Wh = QS;
  char* Wl = QS + 16384;
  char* Xh = QS + 32768;
  char* Xl = QS + 40960;

  const int tid = threadIdx.x;
  const int lane = tid & 63;
  const int w = tid >> 6;
  const int c = lane & 15;
  const int g = lane >> 4;
  const int o0 = blockIdx.x * 128;
  const int p0 = blockIdx.y * 64;
  const int b = blockIdx.z;

  #pragma unroll
  for (int it = 0; it < 4; ++it) {
    int task = tid + it * 256;
    int oct = task & 7, o = task >> 3;
    const f4* wr = (const f4*)(wqkv + (size_t)(o0 + o) * CIN + oct * 8);
    f4 wa = wr[0], wb = wr[1];
    h8 hi, lo;
    #pragma unroll
    for (int e = 0; e < 8; ++e) {
      float v = e < 4 ? wa[e] : wb[e - 4];
      _Float16 h = (_Float16)v;
      hi[e] = h;
      lo[e] = (_Float16)((v - (float)h) * LOSCALE);
    }
    int byo = o * 128 + ((oct ^ (o & 7)) << 4);
    *(h8*)(Wh + byo) = hi;
    *(h8*)(Wl + byo) = lo;
  }
  #pragma unroll
  for (int it = 0; it < 16; ++it) {
    int idx = tid + it * 256;
    int p = idx & 63, cc = idx >> 6;
    float v = x[((size_t)b * CIN + cc) * NPIX + p0 + p];
    _Float16 h = (_Float16)v;
    _Float16 l = (_Float16)((v - (float)h) * LOSCALE);
    int byo = p * 128 + (((cc >> 3) ^ (p & 7)) << 4) + (cc & 7) * 2;
    *(_Float16*)(Xh + byo) = h;
    *(_Float16*)(Xl + byo) = l;
  }
  __syncthreads();

  f4 zf = {0.f, 0.f, 0.f, 0.f};
  f4 acc[2][4], cor[2][4];
  #pragma unroll
  for (int oi = 0; oi < 2; ++oi)
    #pragma unroll
    for (int pi = 0; pi < 4; ++pi) { acc[oi][pi] = zf; cor[oi][pi] = zf; }

  const int ob = w * 32;
  // A-row remap: tile oi, A row r holds W row ob + 8*(r>>2) + (r&3) + 4*oi
  // => C rows (4g+reg) of tiles (0,1) give 8 consecutive d at ob+8g  (b128 store)
  #pragma unroll
  for (int kh = 0; kh < 2; ++kh) {
    h8 ah[2], al[2], bh[4], bl[4];
    #pragma unroll
    for (int oi = 0; oi < 2; ++oi) {
      int orow = ob + ((c >> 2) << 3) + (c & 3) + oi * 4;
      int ch = (((kh * 4 + g) ^ (orow & 7)) << 4);
      ah[oi] = *(const h8*)(Wh + orow * 128 + ch);
      al[oi] = *(const h8*)(Wl + orow * 128 + ch);
    }
    #pragma unroll
    for (int pi = 0; pi < 4; ++pi) {
      int prow = pi * 16 + c;
      int ch = (((kh * 4 + g) ^ (prow & 7)) << 4);
      bh[pi] = *(const h8*)(Xh + prow * 128 + ch);
      bl[pi] = *(const h8*)(Xl + prow * 128 + ch);
    }
    __builtin_amdgcn_s_setprio(1);
    #pragma unroll
    for (int oi = 0; oi < 2; ++oi)
      #pragma unroll
      for (int pi = 0; pi < 4; ++pi) {
        acc[oi][pi] = __builtin_amdgcn_mfma_f32_16x16x32_f16(ah[oi], bh[pi], acc[oi][pi], 0, 0, 0);
        cor[oi][pi] = __builtin_amdgcn_mfma_f32_16x16x32_f16(ah[oi], bl[pi], cor[oi][pi], 0, 0, 0);
        cor[oi][pi] = __builtin_amdgcn_mfma_f32_16x16x32_f16(al[oi], bh[pi], cor[oi][pi], 0, 0, 0);
      }
    __builtin_amdgcn_s_setprio(0);
  }

  const int part = o0 >> 9;
  const float scl = part == 0 ? QSCALE : 1.0f;
  _Float16* dsth = part == 0 ? Qh : (part == 1 ? Kh : Vv);
  _Float16* dstl = part == 0 ? Ql : (part == 1 ? Kl : nullptr);
  #pragma unroll
  for (int pi = 0; pi < 4; ++pi) {
    int obase = o0 + ob + 8 * g;
    int h = (obase >> 6) & 7;
    int d = obase & 63;
    int p_abs = p0 + pi * 16 + c;
    size_t off = (((size_t)(b * NH + h)) * NPIX + p_abs) * DH + d;
    h8 hv, lv;
    #pragma unroll
    for (int oi = 0; oi < 2; ++oi)
      #pragma unroll
      for (int reg = 0; reg < 4; ++reg) {
        float v = (acc[oi][pi][reg] + cor[oi][pi][reg] * INV_LOSCALE) * scl;
        _Float16 hh = (_Float16)v;
        hv[oi * 4 + reg] = hh;
        lv[oi * 4 + reg] = (_Float16)((v - (float)hh) * LOSCALE);
      }
    *(h8*)(dsth + off) = hv;
    if (dstl) *(h8*)(dstl + off) = lv;
  }
}

// ---------------- fused MFMA attention (compensated fp16, async 2-phase) ----
__global__ __launch_bounds__(256, 2) void attn_mfma(
    const _Float16* __restrict__ Qh, const _Float16* __restrict__ Ql,
    const _Float16* __restrict__ Kh, const _Float16* __restrict__ Kl,
    const _Float16* __restrict__ V,
    const float* __restrict__ rel_h, const float* __restrict__ rel_w,
    float* __restrict__ out) {
  __shared__ __align__(16) char SMem[81920];
  char* SMp = SMem + 49152;
  _Float16* LWT16 = (_Float16*)SMp;
  _Float16* LH16 = (_Float16*)(SMem + 65536);
  float* OT = (float*)SMem;

  const int tid = threadIdx.x;
  const int lane = tid & 63;
  const int w = tid >> 6;
  const int wu = __builtin_amdgcn_readfirstlane(w);
  const int c = lane & 15;
  const int g = lane >> 4;
  const int bx = blockIdx.x;
  const int bh = ((bx & 7) << 3) | ((bx >> 3) & 7);
  const int i0 = (bx >> 6) << 7;

  const _Float16* Qhg = Qh + (size_t)bh * NPIX * DH;
  const _Float16* Qlg = Ql + (size_t)bh * NPIX * DH;
  const _Float16* Khg = Kh + (size_t)bh * NPIX * DH;
  const _Float16* Klg = Kl + (size_t)bh * NPIX * DH;
  const _Float16* Vg  = V  + (size_t)bh * NPIX * DH;

  const h8* Qr0h = (const h8*)(Qhg + (size_t)(i0 + w * 32 + c) * DH);
  const h8* Qr0l = (const h8*)(Qlg + (size_t)(i0 + w * 32 + c) * DH);
  const h8* Qr1h = (const h8*)(Qhg + (size_t)(i0 + w * 32 + 16 + c) * DH);
  const h8* Qr1l = (const h8*)(Qlg + (size_t)(i0 + w * 32 + 16 + c) * DH);
  h8 q0h[2] = {Qr0h[g], Qr0h[4 + g]};
  h8 q0l[2] = {Qr0l[g], Qr0l[4 + g]};
  h8 q1h[2] = {Qr1h[g], Qr1h[4 + g]};
  h8 q1l[2] = {Qr1l[g], Qr1l[4 + g]};

  const int s0i = wu * 128 + lane;
  const int s1i = s0i + 64;
  const int ko0 = (s0i >> 3) * 128 + (((s0i & 7) ^ ((s0i >> 3) & 7)) << 4);
  const int ko1 = (s1i >> 3) * 128 + (((s1i & 7) ^ ((s1i >> 3) & 7)) << 4);

  // ---- stage rel tables as fp16 chunks ----
  #pragma unroll
  for (int it = 0; it < 2; ++it) {
    int task = tid + it * 256;
    int oct = task & 7, s = task >> 3;
    int ss = s < 63 ? s : 62;
    const float* sh = rel_h + (size_t)ss * DH + oct * 8;
    const float* sw = rel_w + (size_t)ss * DH + oct * 8;
    h8 hh, ww;
    #pragma unroll
    for (int e = 0; e < 8; ++e) {
      hh[e] = (_Float16)sh[e];
      ww[e] = (_Float16)sw[e];
    }
    int byo = s * 128 + ((oct ^ (s & 7)) << 4);
    *(h8*)(SMem + byo) = hh;
    *(h8*)(SMem + 32768 + byo) = ww;
  }
  __syncthreads();

  // ---- lh/lw logit tables via MFMA (with Qlo correction), fp16 out ----
  f4 zf = {0.f, 0.f, 0.f, 0.f};
  #pragma unroll
  for (int rs = 0; rs < 2; ++rs) {
    f4 lhC[4], lwC[4], lhCc[4], lwCc[4];
    #pragma unroll
    for (int cg = 0; cg < 4; ++cg) { lhC[cg] = zf; lwC[cg] = zf; lhCc[cg] = zf; lwCc[cg] = zf; }
    #pragma unroll
    for (int kh = 0; kh < 2; ++kh) {
      h8 a  = rs ? q1h[kh] : q0h[kh];
      h8 al = rs ? q1l[kh] : q0l[kh];
      #pragma unroll
      for (int cg = 0; cg < 4; ++cg) {
        int s = cg * 16 + c;
        int chb = s * 128 + (((kh * 4 + g) ^ (s & 7)) << 4);
        h8 rb = *(const h8*)(SMem + chb);
        h8 wb = *(const h8*)(SMem + 32768 + chb);
        lhC[cg]  = __builtin_amdgcn_mfma_f32_16x16x32_f16(a,  rb, lhC[cg], 0, 0, 0);
        lhCc[cg] = __builtin_amdgcn_mfma_f32_16x16x32_f16(al, rb, lhCc[cg], 0, 0, 0);
        lwC[cg]  = __builtin_amdgcn_mfma_f32_16x16x32_f16(a,  wb, lwC[cg], 0, 0, 0);
        lwCc[cg] = __builtin_amdgcn_mfma_f32_16x16x32_f16(al, wb, lwCc[cg], 0, 0, 0);
      }
    }
    #pragma unroll
    for (int cg = 0; cg < 4; ++cg)
      #pragma unroll
      for (int reg = 0; reg < 4; ++reg) {
        int r = w * 32 + rs * 16 + 4 * g + reg;
        int col = cg * 16 + c;
        LH16[r * 64 + (col ^ (((r >> 2) & 3) << 4))] =
            (_Float16)(lhC[cg][reg] + lhCc[cg][reg] * INV_LOSCALE);
        LWT16[r * 64 + col] =
            (_Float16)(lwC[cg][reg] + lwCc[cg][reg] * INV_LOSCALE);
      }
  }
  __syncthreads();

  float lw0[4][2], lw1[4][2];
  #pragma unroll
  for (int reg = 0; reg < 4; ++reg) {
    int xi0 = 4 * g + reg;
    int r0 = w * 32 + xi0;
    #pragma unroll
    for (int par = 0; par < 2; ++par) {
      lw0[reg][par] = (float)LWT16[r0 * 64 + 31 + par * 16 + c - xi0];
      lw1[reg][par] = (float)LWT16[(r0 + 16) * 64 + 31 + par * 16 + c - (xi0 + 16)];
    }
  }

  // ---- stage tile 0 ----
  {
    gload_lds16((const char*)Khg + ko0, SMem + wu * 2048);
    gload_lds16((const char*)Khg + ko1, SMem + wu * 2048 + 1024);
    gload_lds16((const char*)Klg + ko0, SMem + 16384 + wu * 2048);
    gload_lds16((const char*)Klg + ko1, SMem + 16384 + wu * 2048 + 1024);
    int jp = tid & 31, dd = tid >> 5;
    const h8* vr = (const h8*)(Vg + (size_t)(2 * jp) * DH);
    h8 v0 = vr[dd], v1 = vr[8 + dd];
    us8 u0 = *(const us8*)&v0, u1 = *(const us8*)&v1;
    #pragma unroll
    for (int e = 0; e < 8; ++e) {
      int d = dd * 8 + e;
      unsigned int val = (unsigned int)u0[e] | ((unsigned int)u1[e] << 16);
      *(unsigned int*)(SMem + 32768 + d * 128 + (((jp >> 2) ^ (d & 7)) << 4) + (jp & 3) * 4) = val;
    }
  }
  __syncthreads();

  const int yi = (i0 >> 5) + w;
  float m0[4], lp0[4], m1[4], lp1[4];
  f4 o0_[4], o1_[4];
  #pragma unroll
  for (int reg = 0; reg < 4; ++reg) { m0[reg] = -1e30f; lp0[reg] = 0.f; m1[reg] = -1e30f; lp1[reg] = 0.f; }
  #pragma unroll
  for (int cg = 0; cg < 4; ++cg) { o0_[cg] = zf; o1_[cg] = zf; }

  int cur = 0;
  #pragma unroll 1
  for (int t = 0; t < 16; ++t) {
    char* Kc  = SMem + cur * 8192;
    char* KLc = SMem + 16384 + cur * 8192;
    char* Vc  = SMem + 32768 + cur * 8192;
    const int nxt = cur ^ 1;
    const bool pre = t < 15;
    const int jp = tid & 31, dd = tid >> 5;
    h8 v0 = {}, v1 = {};
    if (pre) {
      const char* kg  = (const char*)Khg + (size_t)(t + 1) * 8192;
      const char* klg = (const char*)Klg + (size_t)(t + 1) * 8192;
      char* Kn  = SMem + nxt * 8192;
      char* KLn = SMem + 16384 + nxt * 8192;
      gload_lds16(kg + ko0, Kn + wu * 2048);
      gload_lds16(kg + ko1, Kn + wu * 2048 + 1024);
      gload_lds16(klg + ko0, KLn + wu * 2048);
      gload_lds16(klg + ko1, KLn + wu * 2048 + 1024);
      const h8* vr = (const h8*)(Vg + (size_t)((t + 1) * 64 + 2 * jp) * DH);
      v0 = vr[dd];
      v1 = vr[8 + dd];
    }

    // ---- QK^T both rowsets ----
    f4 s0_[4], sc0_[4], s1_[4], sc1_[4];
    #pragma unroll
    for (int cg = 0; cg < 4; ++cg) { s0_[cg] = zf; sc0_[cg] = zf; s1_[cg] = zf; sc1_[cg] = zf; }
    #pragma unroll
    for (int kh = 0; kh < 2; ++kh) {
      h8 a0 = q0h[kh], a0l = q0l[kh], a1 = q1h[kh], a1l = q1l[kh];
      #pragma unroll
      for (int cg = 0; cg < 4; ++cg) {
        int j = cg * 16 + c;
        int chb = j * 128 + (((kh * 4 + g) ^ (j & 7)) << 4);
        h8 kbh = *(const h8*)(Kc + chb);
        h8 kbl = *(const h8*)(KLc + chb);
        __builtin_amdgcn_s_setprio(1);
        s0_[cg]  = __builtin_amdgcn_mfma_f32_16x16x32_f16(a0,  kbh, s0_[cg], 0, 0, 0);
        sc0_[cg] = __builtin_amdgcn_mfma_f32_16x16x32_f16(a0l, kbh, sc0_[cg], 0, 0, 0);
        sc0_[cg] = __builtin_amdgcn_mfma_f32_16x16x32_f16(a0,  kbl, sc0_[cg], 0, 0, 0);
        s1_[cg]  = __builtin_amdgcn_mfma_f32_16x16x32_f16(a1,  kbh, s1_[cg], 0, 0, 0);
        sc1_[cg] = __builtin_amdgcn_mfma_f32_16x16x32_f16(a1l, kbh, sc1_[cg], 0, 0, 0);
        sc1_[cg] = __builtin_amdgcn_mfma_f32_16x16x32_f16(a1,  kbl, sc1_[cg], 0, 0, 0);
        __builtin_amdgcn_s_setprio(0);
      }
    }

    const int lhb = 31 + 2 * t - yi;
    // finish: bias + online softmax (defer-max, deferred l-reduce) + P write
    auto finish = [&](f4* s_, f4* sc_, float (*lw)[2], float* m_s, float* lp,
                      f4* o_, int rs) {
      float lhv[4][2];
      #pragma unroll
      for (int reg = 0; reg < 4; ++reg) {
        int r = w * 32 + rs * 16 + 4 * g + reg;
        int msk = ((r >> 2) & 3) << 4;
        lhv[reg][0] = (float)LH16[r * 64 + (lhb ^ msk)];
        lhv[reg][1] = (float)LH16[r * 64 + ((lhb + 1) ^ msk)];
      }
      #pragma unroll
      for (int cg = 0; cg < 4; ++cg)
        #pragma unroll
        for (int reg = 0; reg < 4; ++reg)
          s_[cg][reg] += sc_[cg][reg] * INV_LOSCALE + lw[reg][cg & 1] + lhv[reg][cg >> 1];
      float tm[4];
      int skip = 1;
      #pragma unroll
      for (int reg = 0; reg < 4; ++reg) {
        float v = fmaxf(fmaxf(s_[0][reg], s_[1][reg]), fmaxf(s_[2][reg], s_[3][reg]));
        v = fmaxf(v, dpp_ror<0x121>(v));
        v = fmaxf(v, dpp_ror<0x122>(v));
        v = fmaxf(v, dpp_ror<0x124>(v));
        v = fmaxf(v, dpp_ror<0x128>(v));
        tm[reg] = v;
        skip &= (v <= m_s[reg] + DTHR) ? 1 : 0;
      }
      float pvv[4][4];
      if (__all(skip)) {   // T13: keep old max, no rescale
        #pragma unroll
        for (int reg = 0; reg < 4; ++reg) {
          float sum = 0.f;
          #pragma unroll
          for (int cg = 0; cg < 4; ++cg) {
            float p = fexp2(s_[cg][reg] - m_s[reg]);
            pvv[cg][reg] = p;
            sum += p;
          }
          lp[reg] += sum;
        }
      } else {
        #pragma unroll
        for (int reg = 0; reg < 4; ++reg) {
          float mn = fmaxf(m_s[reg], tm[reg]);
          float corr = fexp2(m_s[reg] - mn);
          m_s[reg] = mn;
          float sum = 0.f;
          #pragma unroll
          for (int cg = 0; cg < 4; ++cg) {
            float p = fexp2(s_[cg][reg] - mn);
            pvv[cg][reg] = p;
            sum += p;
          }
          lp[reg] = lp[reg] * corr + sum;
          #pragma unroll
          for (int cg = 0; cg < 4; ++cg) o_[cg][reg] *= corr;
        }
      }
      #pragma unroll
      for (int reg = 0; reg < 4; ++reg) {
        int r2 = rs * 16 + 4 * g + reg;
        #pragma unroll
        for (int cg = 0; cg < 4; ++cg) {
          int j = cg * 16 + c;
          *(_Float16*)(SMp + w * 4096 + r2 * 128 + (((j >> 3) ^ (r2 & 7)) << 4) + (j & 7) * 2)
              = (_Float16)pvv[cg][reg];
        }
      }
    };

    finish(s0_, sc0_, lw0, m0, lp0, o0_, 0);
    __builtin_amdgcn_wave_barrier();

    // ---- PV rowset0 (cache V fragments), overlapped with finish rowset1 ----
    h8 vbr[2][4];
    #pragma unroll
    for (int kh = 0; kh < 2; ++kh) {
      int oc = kh * 4 + g;
      h8 pa0 = *(const h8*)(SMp + w * 4096 + c * 128 + ((oc ^ (c & 7)) << 4));
      __builtin_amdgcn_s_setprio(1);
      #pragma unroll
      for (int cgd = 0; cgd < 4; ++cgd) {
        int d = cgd * 16 + c;
        vbr[kh][cgd] = *(const h8*)(Vc + d * 128 + ((oc ^ (d & 7)) << 4));
        o0_[cgd] = __builtin_amdgcn_mfma_f32_16x16x32_f16(pa0, vbr[kh][cgd], o0_[cgd], 0, 0, 0);
      }
      __builtin_amdgcn_s_setprio(0);
    }
    finish(s1_, sc1_, lw1, m1, lp1, o1_, 1);
    __builtin_amdgcn_wave_barrier();

    // ---- PV rowset1 (reuse V fragments) ----
    #pragma unroll
    for (int kh = 0; kh < 2; ++kh) {
      int oc = kh * 4 + g;
      h8 pa1 = *(const h8*)(SMp + w * 4096 + (16 + c) * 128 + ((oc ^ (c & 7)) << 4));
      __builtin_amdgcn_s_setprio(1);
      #pragma unroll
      for (int cgd = 0; cgd < 4; ++cgd)
        o1_[cgd] = __builtin_amdgcn_mfma_f32_16x16x32_f16(pa1, vbr[kh][cgd], o1_[cgd], 0, 0, 0);
      __builtin_amdgcn_s_setprio(0);
    }

    if (pre) {
      us8 u0 = *(const us8*)&v0, u1 = *(const us8*)&v1;
      char* Vn = SMem + 32768 + nxt * 8192;
      #pragma unroll
      for (int e = 0; e < 8; ++e) {
        int d = dd * 8 + e;
        unsigned int val = (unsigned int)u0[e] | ((unsigned int)u1[e] << 16);
        *(unsigned int*)(Vn + d * 128 + (((jp >> 2) ^ (d & 7)) << 4) + (jp & 3) * 4) = val;
      }
    }
    __syncthreads();
    cur = nxt;
  }

  // ---- epilogue: reduce l, normalize, transpose via OT, store ----
  float r0v[4], r1v[4];
  #pragma unroll
  for (int reg = 0; reg < 4; ++reg) {
    float a = lp0[reg];
    a += dpp_ror<0x121>(a);
    a += dpp_ror<0x122>(a);
    a += dpp_ror<0x124>(a);
    a += dpp_ror<0x128>(a);
    r0v[reg] = __builtin_amdgcn_rcpf(a);
    float b = lp1[reg];
    b += dpp_ror<0x121>(b);
    b += dpp_ror<0x122>(b);
    b += dpp_ror<0x124>(b);
    b += dpp_ror<0x128>(b);
    r1v[reg] = __builtin_amdgcn_rcpf(b);
  }
  #pragma unroll
  for (int cgd = 0; cgd < 4; ++cgd)
    #pragma unroll
    for (int reg = 0; reg < 4; ++reg) {
      int d = cgd * 16 + c;
      int sw = (d & 7) << 3;
      int r0 = w * 32 + 4 * g + reg;
      OT[d * 128 + (r0 ^ sw)] = o0_[cgd][reg] * r0v[reg];
      OT[d * 128 + ((r0 + 16) ^ sw)] = o1_[cgd][reg] * r1v[reg];
    }
  __syncthreads();
  #pragma unroll
  for (int it = 0; it < 8; ++it) {
    int task = tid + it * 256;
    int rq = task & 31, d = task >> 5;
    f4 vv = *(const f4*)&OT[d * 128 + ((rq * 4) ^ ((d & 7) << 3))];
    *(f4*)(out + (((size_t)bh * 64 + d) << 10) + i0 + rq * 4) = vv;
  }
}

extern "C" void kernel_launch(void* const* d_in, const int* in_sizes, int n_in,
                              void* d_out, int out_size, void* d_ws, size_t ws_size,
                              hipStream_t stream) {
  const float* x  = (const float*)d_in[0];
  const float* wq = (const float*)d_in[1];
  const float* rh = (const float*)d_in[2];
  const float* rw = (const float*)d_in[3];
  float* out = (float*)d_out;

  const size_t sz = (size_t)NBH * NPIX * DH;
  _Float16* Qh = (_Float16*)d_ws;
  _Float16* Ql = Qh + sz;
  _Float16* Kh = Ql + sz;
  _Float16* Kl = Kh + sz;
  _Float16* V  = Kl + sz;

  qkv_mfma<<<dim3(12, 16, 8), 256, 0, stream>>>(x, wq, Qh, Ql, Kh, Kl, V);
  attn_mfma<<<dim3(512), 256, 0, stream>>>(Qh, Ql, Kh, Kl, V, rh, rw, out);
}

// Round 8
// 79.861 us; speedup vs baseline: 12.2746x; 1.1094x over previous
//
#include <hip/hip_runtime.h>
#include <hip/hip_bf16.h>
#include <hip/hip_fp16.h>

typedef _Float16 h8 __attribute__((ext_vector_type(8)));
typedef _Float16 h2 __attribute__((ext_vector_type(2)));
typedef unsigned short us8 __attribute__((ext_vector_type(8)));
typedef float f4 __attribute__((ext_vector_type(4)));

#define NH 8
#define DH 64
#define NPIX 1024
#define CIN 64
#define NBH 64
// 512 (ref scale) * log2(e): logits come out in base-2 units
#define QSCALE (512.0f * 1.44269504f)
#define LOSCALE 2048.0f
#define INV_LOSCALE (1.0f / 2048.0f)
#define DTHR 12.0f

__device__ __forceinline__ void gload_lds16(const void* g, void* lds) {
  __builtin_amdgcn_global_load_lds(
      (const __attribute__((address_space(1))) void*)g,
      (__attribute__((address_space(3))) void*)lds, 16, 0, 0);
}

__device__ __forceinline__ float fexp2(float x) {
#if __has_builtin(__builtin_amdgcn_exp2f)
  return __builtin_amdgcn_exp2f(x);
#else
  return exp2f(x);
#endif
}

__device__ __forceinline__ unsigned pk16(float a, float b) {
  auto r = __builtin_amdgcn_cvt_pkrtz(a, b);   // __fp16 ext_vector(2)
  union { decltype(r) h; unsigned u; } x;
  x.h = r;
  return x.u;
}

__device__ __forceinline__ f4 max4(f4 a, f4 b) {
  f4 r;
  r[0] = fmaxf(a[0], b[0]); r[1] = fmaxf(a[1], b[1]);
  r[2] = fmaxf(a[2], b[2]); r[3] = fmaxf(a[3], b[3]);
  return r;
}

// ---------------- QKV projection via compensated fp16 MFMA ----------------
__global__ __launch_bounds__(256) void qkv_mfma(
    const float* __restrict__ x, const float* __restrict__ wqkv,
    _Float16* __restrict__ Qh, _Float16* __restrict__ Ql,
    _Float16* __restrict__ Kh, _Float16* __restrict__ Kl,
    _Float16* __restrict__ Vv) {
  __shared__ __align__(16) char QS[49152];
  char* Wh = QS;
  char* Wl = QS + 16384;
  char* Xh = QS + 32768;
  char* Xl = QS + 40960;

  const int tid = threadIdx.x;
  const int lane = tid & 63;
  const int w = tid >> 6;
  const int c = lane & 15;
  const int g = lane >> 4;
  const int o0 = blockIdx.x * 128;
  const int p0 = blockIdx.y * 64;
  const int b = blockIdx.z;

  #pragma unroll
  for (int it = 0; it < 4; ++it) {
    int task = tid + it * 256;
    int oct = task & 7, o = task >> 3;
    const f4* wr = (const f4*)(wqkv + (size_t)(o0 + o) * CIN + oct * 8);
    f4 wa = wr[0], wb = wr[1];
    h8 hi, lo;
    #pragma unroll
    for (int e = 0; e < 8; ++e) {
      float v = e < 4 ? wa[e] : wb[e - 4];
      _Float16 h = (_Float16)v;
      hi[e] = h;
      lo[e] = (_Float16)((v - (float)h) * LOSCALE);
    }
    int byo = o * 128 + ((oct ^ (o & 7)) << 4);
    *(h8*)(Wh + byo) = hi;
    *(h8*)(Wl + byo) = lo;
  }
  #pragma unroll
  for (int it = 0; it < 16; ++it) {
    int idx = tid + it * 256;
    int p = idx & 63, cc = idx >> 6;
    float v = x[((size_t)b * CIN + cc) * NPIX + p0 + p];
    _Float16 h = (_Float16)v;
    _Float16 l = (_Float16)((v - (float)h) * LOSCALE);
    int byo = p * 128 + (((cc >> 3) ^ (p & 7)) << 4) + (cc & 7) * 2;
    *(_Float16*)(Xh + byo) = h;
    *(_Float16*)(Xl + byo) = l;
  }
  __syncthreads();

  f4 zf = {0.f, 0.f, 0.f, 0.f};
  f4 acc[2][4], cor[2][4];
  #pragma unroll
  for (int oi = 0; oi < 2; ++oi)
    #pragma unroll
    for (int pi = 0; pi < 4; ++pi) { acc[oi][pi] = zf; cor[oi][pi] = zf; }

  const int ob = w * 32;
  #pragma unroll
  for (int kh = 0; kh < 2; ++kh) {
    h8 ah[2], al[2], bh[4], bl[4];
    #pragma unroll
    for (int oi = 0; oi < 2; ++oi) {
      int orow = ob + ((c >> 2) << 3) + (c & 3) + oi * 4;
      int ch = (((kh * 4 + g) ^ (orow & 7)) << 4);
      ah[oi] = *(const h8*)(Wh + orow * 128 + ch);
      al[oi] = *(const h8*)(Wl + orow * 128 + ch);
    }
    #pragma unroll
    for (int pi = 0; pi < 4; ++pi) {
      int prow = pi * 16 + c;
      int ch = (((kh * 4 + g) ^ (prow & 7)) << 4);
      bh[pi] = *(const h8*)(Xh + prow * 128 + ch);
      bl[pi] = *(const h8*)(Xl + prow * 128 + ch);
    }
    __builtin_amdgcn_s_setprio(1);
    #pragma unroll
    for (int oi = 0; oi < 2; ++oi)
      #pragma unroll
      for (int pi = 0; pi < 4; ++pi) {
        acc[oi][pi] = __builtin_amdgcn_mfma_f32_16x16x32_f16(ah[oi], bh[pi], acc[oi][pi], 0, 0, 0);
        cor[oi][pi] = __builtin_amdgcn_mfma_f32_16x16x32_f16(ah[oi], bl[pi], cor[oi][pi], 0, 0, 0);
        cor[oi][pi] = __builtin_amdgcn_mfma_f32_16x16x32_f16(al[oi], bh[pi], cor[oi][pi], 0, 0, 0);
      }
    __builtin_amdgcn_s_setprio(0);
  }

  const int part = o0 >> 9;
  const float scl = part == 0 ? QSCALE : 1.0f;
  _Float16* dsth = part == 0 ? Qh : (part == 1 ? Kh : Vv);
  _Float16* dstl = part == 0 ? Ql : (part == 1 ? Kl : nullptr);
  #pragma unroll
  for (int pi = 0; pi < 4; ++pi) {
    int obase = o0 + ob + 8 * g;
    int h = (obase >> 6) & 7;
    int d = obase & 63;
    int p_abs = p0 + pi * 16 + c;
    size_t off = (((size_t)(b * NH + h)) * NPIX + p_abs) * DH + d;
    h8 hv, lv;
    #pragma unroll
    for (int oi = 0; oi < 2; ++oi)
      #pragma unroll
      for (int reg = 0; reg < 4; ++reg) {
        float v = (acc[oi][pi][reg] + cor[oi][pi][reg] * INV_LOSCALE) * scl;
        _Float16 hh = (_Float16)v;
        hv[oi * 4 + reg] = hh;
        lv[oi * 4 + reg] = (_Float16)((v - (float)hh) * LOSCALE);
      }
    *(h8*)(dsth + off) = hv;
    if (dstl) *(h8*)(dstl + off) = lv;
  }
}

// ---------------- fused MFMA attention (swapped QK^T, lane-local rows) ----
// LDS (64KB): KH[2] 0..16K | KL[2] 16K..32K | VB[2] 32K..48K | SP 48K..56K
//             LHc 56K..64K.  Prologue: rel_h->KH0, rel_w->KL0, LWT->VB.
__global__ __launch_bounds__(256, 2) void attn_mfma(
    const _Float16* __restrict__ Qh, const _Float16* __restrict__ Ql,
    const _Float16* __restrict__ Kh, const _Float16* __restrict__ Kl,
    const _Float16* __restrict__ V,
    const float* __restrict__ rel_h, const float* __restrict__ rel_w,
    float* __restrict__ out) {
  __shared__ __align__(16) char SMem[65536];
  char* SP = SMem + 49152;
  _Float16* LHc = (_Float16*)(SMem + 57344);  // [128][32] fp16
  _Float16* LWT = (_Float16*)(SMem + 32768);  // prologue temp [128][64]
  float* OT = (float*)SMem;                   // epilogue [64][128] f32

  const int tid = threadIdx.x;
  const int lane = tid & 63;
  const int w = tid >> 6;
  const int wu = __builtin_amdgcn_readfirstlane(w);
  const int c = lane & 15;
  const int g = lane >> 4;
  const int bx = blockIdx.x;
  const int bh = ((bx & 7) << 3) | ((bx >> 3) & 7);
  const int i0 = (bx >> 6) << 7;
  const int swz = (c & 7) << 4;

  const _Float16* Qhg = Qh + (size_t)bh * NPIX * DH;
  const _Float16* Qlg = Ql + (size_t)bh * NPIX * DH;
  const _Float16* Khg = Kh + (size_t)bh * NPIX * DH;
  const _Float16* Klg = Kl + (size_t)bh * NPIX * DH;
  const _Float16* Vg  = V  + (size_t)bh * NPIX * DH;

  // Q fragments (used as B operand: B[col=c] = Q[i = base+c][d-octet])
  const h8* Qr0h = (const h8*)(Qhg + (size_t)(i0 + w * 32 + c) * DH);
  const h8* Qr0l = (const h8*)(Qlg + (size_t)(i0 + w * 32 + c) * DH);
  const h8* Qr1h = (const h8*)(Qhg + (size_t)(i0 + w * 32 + 16 + c) * DH);
  const h8* Qr1l = (const h8*)(Qlg + (size_t)(i0 + w * 32 + 16 + c) * DH);
  h8 q0h[2] = {Qr0h[g], Qr0h[4 + g]};
  h8 q0l[2] = {Qr0l[g], Qr0l[4 + g]};
  h8 q1h[2] = {Qr1h[g], Qr1h[4 + g]};
  h8 q1l[2] = {Qr1l[g], Qr1l[4 + g]};

  // K staging: pre-swizzled per-lane global byte offsets (linear LDS dest)
  const int s0i = wu * 128 + lane;
  const int s1i = s0i + 64;
  const int ko0 = (s0i >> 3) * 128 + (((s0i & 7) ^ ((s0i >> 3) & 7)) << 4);
  const int ko1 = (s1i >> 3) * 128 + (((s1i & 7) ^ ((s1i >> 3) & 7)) << 4);

  // ---- stage rel tables as fp16 chunks: rel_h -> KH0, rel_w -> KL0 ----
  #pragma unroll
  for (int it = 0; it < 2; ++it) {
    int task = tid + it * 256;
    int oct = task & 7, s = task >> 3;
    int ss = s < 63 ? s : 62;
    const float* sh = rel_h + (size_t)ss * DH + oct * 8;
    const float* sw = rel_w + (size_t)ss * DH + oct * 8;
    h8 hh, ww;
    #pragma unroll
    for (int e = 0; e < 8; ++e) {
      hh[e] = (_Float16)sh[e];
      ww[e] = (_Float16)sw[e];
    }
    int byo = s * 128 + ((oct ^ (s & 7)) << 4);
    *(h8*)(SMem + byo) = hh;
    *(h8*)(SMem + 16384 + byo) = ww;
  }
  __syncthreads();

  // ---- lh/lw tables via swapped MFMA: D[s-local=4g+reg][i=c] ----
  const int yi = (i0 + w * 32) >> 5;   // same for both rowsets
  f4 zf = {0.f, 0.f, 0.f, 0.f};
  #pragma unroll
  for (int rs = 0; rs < 2; ++rs) {
    f4 lhD[4], lwD[4], lhDc[4], lwDc[4];
    #pragma unroll
    for (int st = 0; st < 4; ++st) { lhD[st] = zf; lwD[st] = zf; lhDc[st] = zf; lwDc[st] = zf; }
    #pragma unroll
    for (int kh = 0; kh < 2; ++kh) {
      h8 bq = rs ? q1h[kh] : q0h[kh];
      h8 bl = rs ? q1l[kh] : q0l[kh];
      #pragma unroll
      for (int st = 0; st < 4; ++st) {
        int srow = st * 16 + c;
        int chb = srow * 128 + (((kh * 4 + g) ^ (srow & 7)) << 4);
        h8 ra = *(const h8*)(SMem + chb);
        h8 wa = *(const h8*)(SMem + 16384 + chb);
        lhD[st]  = __builtin_amdgcn_mfma_f32_16x16x32_f16(ra, bq, lhD[st], 0, 0, 0);
        lhDc[st] = __builtin_amdgcn_mfma_f32_16x16x32_f16(ra, bl, lhDc[st], 0, 0, 0);
        lwD[st]  = __builtin_amdgcn_mfma_f32_16x16x32_f16(wa, bq, lwD[st], 0, 0, 0);
        lwDc[st] = __builtin_amdgcn_mfma_f32_16x16x32_f16(wa, bl, lwDc[st], 0, 0, 0);
      }
    }
    int lrow = w * 32 + rs * 16 + c;
    #pragma unroll
    for (int st = 0; st < 4; ++st)
      #pragma unroll
      for (int reg = 0; reg < 4; ++reg) {
        int s = st * 16 + 4 * g + reg;
        float lhv = lhD[st][reg] + lhDc[st][reg] * INV_LOSCALE;
        float lwv = lwD[st][reg] + lwDc[st][reg] * INV_LOSCALE;
        int k = s - 31 + yi;
        if (k >= 0 && k < 32) LHc[lrow * 32 + k] = (_Float16)lhv;
        LWT[lrow * 64 + s] = (_Float16)lwv;
      }
  }
  __syncthreads();

  // lw registers: lwp[rs][jbp*4+reg] = lw[i][31 + jbp*16 + 4g+reg - xi]
  h8 lwp0, lwp1;
  #pragma unroll
  for (int jbp = 0; jbp < 2; ++jbp)
    #pragma unroll
    for (int reg = 0; reg < 4; ++reg) {
      lwp0[jbp * 4 + reg] = LWT[(w * 32 + c) * 64 + 31 + jbp * 16 + 4 * g + reg - c];
      lwp1[jbp * 4 + reg] = LWT[(w * 32 + 16 + c) * 64 + 31 + jbp * 16 + 4 * g + reg - 16 - c];
    }
  __syncthreads();

  // ---- stage tile 0 (K gloads -> buf0; V reg->LDS buf0) ----
  {
    gload_lds16((const char*)Khg + ko0, SMem + wu * 2048);
    gload_lds16((const char*)Khg + ko1, SMem + wu * 2048 + 1024);
    gload_lds16((const char*)Klg + ko0, SMem + 16384 + wu * 2048);
    gload_lds16((const char*)Klg + ko1, SMem + 16384 + wu * 2048 + 1024);
    int jp = tid & 31, dd = tid >> 5;
    const h8* vr = (const h8*)(Vg + (size_t)(2 * jp) * DH);
    h8 v0 = vr[dd], v1 = vr[8 + dd];
    us8 u0 = *(const us8*)&v0, u1 = *(const us8*)&v1;
    #pragma unroll
    for (int e = 0; e < 8; ++e) {
      int d = dd * 8 + e;
      unsigned int val = (unsigned int)u0[e] | ((unsigned int)u1[e] << 16);
      *(unsigned int*)(SMem + 32768 + d * 128 + (((jp >> 2) ^ (d & 7)) << 4) + (jp & 3) * 4) = val;
    }
  }
  __syncthreads();

  float m0 = -1e30f, m1 = -1e30f, lp0 = 0.f, lp1 = 0.f;
  f4 o0_[4], o1_[4];
  #pragma unroll
  for (int dt = 0; dt < 4; ++dt) { o0_[dt] = zf; o1_[dt] = zf; }

  int cur = 0;
  #pragma unroll 1
  for (int t = 0; t < 16; ++t) {
    char* Kc  = SMem + cur * 8192;
    char* KLc = SMem + 16384 + cur * 8192;
    char* Vc  = SMem + 32768 + cur * 8192;
    const int nxt = cur ^ 1;
    const bool pre = t < 15;
    const int jp = tid & 31, dd = tid >> 5;
    h8 v0 = {}, v1 = {};
    if (pre) {   // issue next-tile loads early (latency hides under QK)
      const char* kg  = (const char*)Khg + (size_t)(t + 1) * 8192;
      const char* klg = (const char*)Klg + (size_t)(t + 1) * 8192;
      gload_lds16(kg + ko0, SMem + nxt * 8192 + wu * 2048);
      gload_lds16(kg + ko1, SMem + nxt * 8192 + wu * 2048 + 1024);
      gload_lds16(klg + ko0, SMem + 16384 + nxt * 8192 + wu * 2048);
      gload_lds16(klg + ko1, SMem + 16384 + nxt * 8192 + wu * 2048 + 1024);
      const h8* vr = (const h8*)(Vg + (size_t)((t + 1) * 64 + 2 * jp) * DH);
      v0 = vr[dd];
      v1 = vr[8 + dd];
    }

    // ---- QK^T swapped: sX[jb][reg] = S[i = base+c][j = t*64+jb*16+4g+reg]
    f4 s0[4], c0[4], s1[4], c1[4];
    #pragma unroll
    for (int jb = 0; jb < 4; ++jb) { s0[jb] = zf; c0[jb] = zf; s1[jb] = zf; c1[jb] = zf; }
    #pragma unroll
    for (int kh = 0; kh < 2; ++kh) {
      h8 b0h = q0h[kh], b0l = q0l[kh], b1h = q1h[kh], b1l = q1l[kh];
      #pragma unroll
      for (int jb = 0; jb < 4; ++jb) {
        int jrow = jb * 16 + c;
        int chb = jrow * 128 + (((kh * 4 + g) ^ (c & 7)) << 4);
        h8 ah = *(const h8*)(Kc + chb);
        h8 al = *(const h8*)(KLc + chb);
        __builtin_amdgcn_s_setprio(1);
        s0[jb] = __builtin_amdgcn_mfma_f32_16x16x32_f16(ah, b0h, s0[jb], 0, 0, 0);
        c0[jb] = __builtin_amdgcn_mfma_f32_16x16x32_f16(al, b0h, c0[jb], 0, 0, 0);
        c0[jb] = __builtin_amdgcn_mfma_f32_16x16x32_f16(ah, b0l, c0[jb], 0, 0, 0);
        s1[jb] = __builtin_amdgcn_mfma_f32_16x16x32_f16(ah, b1h, s1[jb], 0, 0, 0);
        c1[jb] = __builtin_amdgcn_mfma_f32_16x16x32_f16(al, b1h, c1[jb], 0, 0, 0);
        c1[jb] = __builtin_amdgcn_mfma_f32_16x16x32_f16(ah, b1l, c1[jb], 0, 0, 0);
        __builtin_amdgcn_s_setprio(0);
      }
    }

    // finish: bias + online softmax (scalar state) + packed P write
    auto finish = [&](f4* s_, f4* c_, const h8& lwp, float& m_s, float& lp,
                      f4* o_, int rs) {
      h2 lhu = *(const h2*)(LHc + (w * 32 + rs * 16 + c) * 32 + 2 * t);
      float lh01[2] = {(float)lhu[0], (float)lhu[1]};
      #pragma unroll
      for (int jb = 0; jb < 4; ++jb)
        #pragma unroll
        for (int reg = 0; reg < 4; ++reg)
          s_[jb][reg] += c_[jb][reg] * INV_LOSCALE +
                         (float)lwp[(jb & 1) * 4 + reg] + lh01[jb >> 1];
      f4 ab = max4(s_[0], s_[1]);
      f4 cd = max4(s_[2], s_[3]);
      f4 ef = max4(ab, cd);
      float mx = fmaxf(fmaxf(ef[0], ef[1]), fmaxf(ef[2], ef[3]));
      mx = fmaxf(mx, __shfl_xor(mx, 16, 64));
      mx = fmaxf(mx, __shfl_xor(mx, 32, 64));
      bool sk = mx <= m_s + DTHR;      // T13 defer-max
      if (!__all(sk)) {
        float mn = fmaxf(m_s, mx);
        float corr = fexp2(m_s - mn);
        m_s = mn;
        lp *= corr;
        #pragma unroll
        for (int dt = 0; dt < 4; ++dt)
          #pragma unroll
          for (int reg = 0; reg < 4; ++reg)
            o_[dt][reg] *= corr;
      }
      float sum = 0.f;
      char* pbse = SP + w * 2048 + c * 128;
      #pragma unroll
      for (int jb = 0; jb < 4; ++jb) {
        f4 p;
        #pragma unroll
        for (int reg = 0; reg < 4; ++reg) {
          p[reg] = fexp2(s_[jb][reg] - m_s);
          sum += p[reg];
        }
        *(unsigned*)(pbse + ((jb * 32 + 8 * g) ^ swz)) = pk16(p[0], p[1]);
        *(unsigned*)(pbse + ((jb * 32 + 8 * g + 4) ^ swz)) = pk16(p[2], p[3]);
      }
      lp += sum;
    };

    finish(s0, c0, lwp0, m0, lp0, o0_, 0);
    __builtin_amdgcn_wave_barrier();

    // ---- PV rowset0 (swapped: A=V, B=P), cache V fragments ----
    h8 vbr[2][4];
    #pragma unroll
    for (int kh = 0; kh < 2; ++kh) {
      int och = ((kh * 4 + g) ^ (c & 7)) << 4;
      h8 pb = *(const h8*)(SP + w * 2048 + c * 128 + och);
      __builtin_amdgcn_s_setprio(1);
      #pragma unroll
      for (int dt = 0; dt < 4; ++dt) {
        vbr[kh][dt] = *(const h8*)(Vc + (dt * 16 + c) * 128 + och);
        o0_[dt] = __builtin_amdgcn_mfma_f32_16x16x32_f16(vbr[kh][dt], pb, o0_[dt], 0, 0, 0);
      }
      __builtin_amdgcn_s_setprio(0);
    }
    __builtin_amdgcn_wave_barrier();

    finish(s1, c1, lwp1, m1, lp1, o1_, 1);
    __builtin_amdgcn_wave_barrier();

    // ---- PV rowset1 (reuse V fragments) ----
    #pragma unroll
    for (int kh = 0; kh < 2; ++kh) {
      int och = ((kh * 4 + g) ^ (c & 7)) << 4;
      h8 pb = *(const h8*)(SP + w * 2048 + c * 128 + och);
      __builtin_amdgcn_s_setprio(1);
      #pragma unroll
      for (int dt = 0; dt < 4; ++dt)
        o1_[dt] = __builtin_amdgcn_mfma_f32_16x16x32_f16(vbr[kh][dt], pb, o1_[dt], 0, 0, 0);
      __builtin_amdgcn_s_setprio(0);
    }

    if (pre) {   // T14: write prefetched V after compute
      us8 u0 = *(const us8*)&v0, u1 = *(const us8*)&v1;
      char* Vn = SMem + 32768 + nxt * 8192;
      #pragma unroll
      for (int e = 0; e < 8; ++e) {
        int d = dd * 8 + e;
        unsigned int val = (unsigned int)u0[e] | ((unsigned int)u1[e] << 16);
        *(unsigned int*)(Vn + d * 128 + (((jp >> 2) ^ (d & 7)) << 4) + (jp & 3) * 4) = val;
      }
    }
    __syncthreads();
    cur = nxt;
  }

  // ---- epilogue: reduce l across g, normalize, transpose via OT, store ----
  float a0 = lp0;
  a0 += __shfl_xor(a0, 16, 64);
  a0 += __shfl_xor(a0, 32, 64);
  float r0 = __builtin_amdgcn_rcpf(a0);
  float a1 = lp1;
  a1 += __shfl_xor(a1, 16, 64);
  a1 += __shfl_xor(a1, 32, 64);
  float r1 = __builtin_amdgcn_rcpf(a1);
  #pragma unroll
  for (int dt = 0; dt < 4; ++dt)
    #pragma unroll
    for (int reg = 0; reg < 4; ++reg) {
      int d = dt * 16 + 4 * g + reg;
      int sw = (d & 7) << 3;
      int il0 = w * 32 + c;
      OT[d * 128 + (il0 ^ sw)] = o0_[dt][reg] * r0;
      OT[d * 128 + ((il0 + 16) ^ sw)] = o1_[dt][reg] * r1;
    }
  __syncthreads();
  #pragma unroll
  for (int it = 0; it < 8; ++it) {
    int task = tid + it * 256;
    int rq = task & 31, d = task >> 5;
    f4 vv = *(const f4*)&OT[d * 128 + ((rq * 4) ^ ((d & 7) << 3))];
    *(f4*)(out + (((size_t)bh * 64 + d) << 10) + i0 + rq * 4) = vv;
  }
}

extern "C" void kernel_launch(void* const* d_in, const int* in_sizes, int n_in,
                              void* d_out, int out_size, void* d_ws, size_t ws_size,
                              hipStream_t stream) {
  const float* x  = (const float*)d_in[0];
  const float* wq = (const float*)d_in[1];
  const float* rh = (const float*)d_in[2];
  const float* rw = (const float*)d_in[3];
  float* out = (float*)d_out;

  const size_t sz = (size_t)NBH * NPIX * DH;
  _Float16* Qh = (_Float16*)d_ws;
  _Float16* Ql = Qh + sz;
  _Float16* Kh = Ql + sz;
  _Float16* Kl = Kh + sz;
  _Float16* V  = Kl + sz;

  qkv_mfma<<<dim3(12, 16, 8), 256, 0, stream>>>(x, wq, Qh, Ql, Kh, Kl, V);
  attn_mfma<<<dim3(512), 256, 0, stream>>>(Qh, Ql, Kh, Kl, V, rh, rw, out);
}

// Round 9
// 77.916 us; speedup vs baseline: 12.5809x; 1.0250x over previous
//
#include <hip/hip_runtime.h>
#include <hip/hip_bf16.h>
#include <hip/hip_fp16.h>

typedef _Float16 h8 __attribute__((ext_vector_type(8)));
typedef _Float16 h2 __attribute__((ext_vector_type(2)));
typedef unsigned short us8 __attribute__((ext_vector_type(8)));
typedef float f4 __attribute__((ext_vector_type(4)));

#define NH 8
#define DH 64
#define NPIX 1024
#define CIN 64
#define NBH 64
// 512 (ref scale) * log2(e): logits come out in base-2 units
#define QSCALE (512.0f * 1.44269504f)
#define LOSCALE 2048.0f
#define INV_LOSCALE (1.0f / 2048.0f)
#define DTHR 12.0f

__device__ __forceinline__ void gload_lds16(const void* g, void* lds) {
  __builtin_amdgcn_global_load_lds(
      (const __attribute__((address_space(1))) void*)g,
      (__attribute__((address_space(3))) void*)lds, 16, 0, 0);
}

__device__ __forceinline__ float fexp2(float x) {
#if __has_builtin(__builtin_amdgcn_exp2f)
  return __builtin_amdgcn_exp2f(x);
#else
  return exp2f(x);
#endif
}

__device__ __forceinline__ unsigned pk16(float a, float b) {
  auto r = __builtin_amdgcn_cvt_pkrtz(a, b);   // __fp16 ext_vector(2)
  union { decltype(r) h; unsigned u; } x;
  x.h = r;
  return x.u;
}

__device__ __forceinline__ f4 max4(f4 a, f4 b) {
  f4 r;
  r[0] = fmaxf(a[0], b[0]); r[1] = fmaxf(a[1], b[1]);
  r[2] = fmaxf(a[2], b[2]); r[3] = fmaxf(a[3], b[3]);
  return r;
}

// ---------------- QKV projection via compensated fp16 MFMA ----------------
__global__ __launch_bounds__(256) void qkv_mfma(
    const float* __restrict__ x, const float* __restrict__ wqkv,
    _Float16* __restrict__ Qh, _Float16* __restrict__ Ql,
    _Float16* __restrict__ Kh, _Float16* __restrict__ Kl,
    _Float16* __restrict__ Vv) {
  __shared__ __align__(16) char QS[49152];
  char* Wh = QS;
  char* Wl = QS + 16384;
  char* Xh = QS + 32768;
  char* Xl = QS + 40960;

  const int tid = threadIdx.x;
  const int lane = tid & 63;
  const int w = tid >> 6;
  const int c = lane & 15;
  const int g = lane >> 4;
  const int o0 = blockIdx.x * 128;
  const int p0 = blockIdx.y * 64;
  const int b = blockIdx.z;

  // ---- stage W tile (hi/lo fp16, chunked+swizzled, b128 conflict-free) ----
  #pragma unroll
  for (int it = 0; it < 4; ++it) {
    int task = tid + it * 256;
    int oct = task & 7, o = task >> 3;
    const f4* wr = (const f4*)(wqkv + (size_t)(o0 + o) * CIN + oct * 8);
    f4 wa = wr[0], wb = wr[1];
    h8 hi, lo;
    #pragma unroll
    for (int e = 0; e < 8; ++e) {
      float v = e < 4 ? wa[e] : wb[e - 4];
      _Float16 h = (_Float16)v;
      hi[e] = h;
      lo[e] = (_Float16)((v - (float)h) * LOSCALE);
    }
    int byo = o * 128 + ((oct ^ (o & 7)) << 4);
    *(h8*)(Wh + byo) = hi;
    *(h8*)(Wl + byo) = lo;
  }
  // ---- stage X transposed via c-pair-packed u32 (conflict-free banks) ----
  {
    int kp = tid & 31;      // c-pair: channels 2kp, 2kp+1
    int pgrp = tid >> 5;    // p-octet 0..7
    const float* xr0 = x + ((size_t)b * CIN + 2 * kp) * NPIX + p0 + pgrp * 8;
    const float* xr1 = xr0 + NPIX;
    f4 a0 = *(const f4*)xr0, a1 = *(const f4*)(xr0 + 4);
    f4 b0 = *(const f4*)xr1, b1 = *(const f4*)(xr1 + 4);
    int oct = kp >> 2;
    int slot4 = (kp & 3) * 4;
    #pragma unroll
    for (int e = 0; e < 8; ++e) {
      float v0 = e < 4 ? a0[e] : a1[e - 4];
      float v1 = e < 4 ? b0[e] : b1[e - 4];
      _Float16 h0 = (_Float16)v0, h1 = (_Float16)v1;
      float l0f = (v0 - (float)h0) * LOSCALE;
      float l1f = (v1 - (float)h1) * LOSCALE;
      int p = pgrp * 8 + e;
      int byo = p * 128 + ((oct ^ (p & 7)) << 4) + slot4;
      union { h2 h; unsigned u; } uh, ul;
      uh.h[0] = h0; uh.h[1] = h1;
      ul.h[0] = (_Float16)l0f; ul.h[1] = (_Float16)l1f;
      *(unsigned*)(Xh + byo) = uh.u;
      *(unsigned*)(Xl + byo) = ul.u;
    }
  }
  __syncthreads();

  f4 zf = {0.f, 0.f, 0.f, 0.f};
  f4 acc[2][4], cor[2][4];
  #pragma unroll
  for (int oi = 0; oi < 2; ++oi)
    #pragma unroll
    for (int pi = 0; pi < 4; ++pi) { acc[oi][pi] = zf; cor[oi][pi] = zf; }

  const int ob = w * 32;
  #pragma unroll
  for (int kh = 0; kh < 2; ++kh) {
    h8 ah[2], al[2], bh[4], bl[4];
    #pragma unroll
    for (int oi = 0; oi < 2; ++oi) {
      int orow = ob + ((c >> 2) << 3) + (c & 3) + oi * 4;
      int ch = (((kh * 4 + g) ^ (orow & 7)) << 4);
      ah[oi] = *(const h8*)(Wh + orow * 128 + ch);
      al[oi] = *(const h8*)(Wl + orow * 128 + ch);
    }
    #pragma unroll
    for (int pi = 0; pi < 4; ++pi) {
      int prow = pi * 16 + c;
      int ch = (((kh * 4 + g) ^ (prow & 7)) << 4);
      bh[pi] = *(const h8*)(Xh + prow * 128 + ch);
      bl[pi] = *(const h8*)(Xl + prow * 128 + ch);
    }
    __builtin_amdgcn_s_setprio(1);
    #pragma unroll
    for (int oi = 0; oi < 2; ++oi)
      #pragma unroll
      for (int pi = 0; pi < 4; ++pi) {
        acc[oi][pi] = __builtin_amdgcn_mfma_f32_16x16x32_f16(ah[oi], bh[pi], acc[oi][pi], 0, 0, 0);
        cor[oi][pi] = __builtin_amdgcn_mfma_f32_16x16x32_f16(ah[oi], bl[pi], cor[oi][pi], 0, 0, 0);
        cor[oi][pi] = __builtin_amdgcn_mfma_f32_16x16x32_f16(al[oi], bh[pi], cor[oi][pi], 0, 0, 0);
      }
    __builtin_amdgcn_s_setprio(0);
  }

  const int part = o0 >> 9;
  const float scl = part == 0 ? QSCALE : 1.0f;
  _Float16* dsth = part == 0 ? Qh : (part == 1 ? Kh : Vv);
  _Float16* dstl = part == 0 ? Ql : (part == 1 ? Kl : nullptr);
  #pragma unroll
  for (int pi = 0; pi < 4; ++pi) {
    int obase = o0 + ob + 8 * g;
    int h = (obase >> 6) & 7;
    int d = obase & 63;
    int p_abs = p0 + pi * 16 + c;
    size_t off = (((size_t)(b * NH + h)) * NPIX + p_abs) * DH + d;
    h8 hv, lv;
    #pragma unroll
    for (int oi = 0; oi < 2; ++oi)
      #pragma unroll
      for (int reg = 0; reg < 4; ++reg) {
        float v = (acc[oi][pi][reg] + cor[oi][pi][reg] * INV_LOSCALE) * scl;
        _Float16 hh = (_Float16)v;
        hv[oi * 4 + reg] = hh;
        lv[oi * 4 + reg] = (_Float16)((v - (float)hh) * LOSCALE);
      }
    *(h8*)(dsth + off) = hv;
    if (dstl) *(h8*)(dstl + off) = lv;
  }
}

// ---------------- fused MFMA attention (swapped QK^T, lane-local rows) ----
// LDS (64KB): KH[2] 0..16K | KL[2] 16K..32K | VB[2] 32K..48K | SP 48K..56K
//             LHc 56K..64K ([32 k][128 rows] fp16).
__global__ __launch_bounds__(256, 2) void attn_mfma(
    const _Float16* __restrict__ Qh, const _Float16* __restrict__ Ql,
    const _Float16* __restrict__ Kh, const _Float16* __restrict__ Kl,
    const _Float16* __restrict__ V,
    const float* __restrict__ rel_h, const float* __restrict__ rel_w,
    float* __restrict__ out) {
  __shared__ __align__(16) char SMem[65536];
  char* SP = SMem + 49152;
  _Float16* LHc = (_Float16*)(SMem + 57344);  // [32 k][128 rows] fp16
  _Float16* LWT = (_Float16*)(SMem + 32768);  // prologue temp [128][64]
  float* OT = (float*)SMem;                   // epilogue [64][128] f32

  const int tid = threadIdx.x;
  const int lane = tid & 63;
  const int w = tid >> 6;
  const int wu = __builtin_amdgcn_readfirstlane(w);
  const int c = lane & 15;
  const int g = lane >> 4;
  const int bx = blockIdx.x;
  const int bh = ((bx & 7) << 3) | ((bx >> 3) & 7);
  const int i0 = (bx >> 6) << 7;
  const int swz = (c & 7) << 4;

  const _Float16* Qhg = Qh + (size_t)bh * NPIX * DH;
  const _Float16* Qlg = Ql + (size_t)bh * NPIX * DH;
  const _Float16* Khg = Kh + (size_t)bh * NPIX * DH;
  const _Float16* Klg = Kl + (size_t)bh * NPIX * DH;
  const _Float16* Vg  = V  + (size_t)bh * NPIX * DH;

  // Q fragments (used as B operand: B[col=c] = Q[i = base+c][d-octet])
  const h8* Qr0h = (const h8*)(Qhg + (size_t)(i0 + w * 32 + c) * DH);
  const h8* Qr0l = (const h8*)(Qlg + (size_t)(i0 + w * 32 + c) * DH);
  const h8* Qr1h = (const h8*)(Qhg + (size_t)(i0 + w * 32 + 16 + c) * DH);
  const h8* Qr1l = (const h8*)(Qlg + (size_t)(i0 + w * 32 + 16 + c) * DH);
  h8 q0h[2] = {Qr0h[g], Qr0h[4 + g]};
  h8 q0l[2] = {Qr0l[g], Qr0l[4 + g]};
  h8 q1h[2] = {Qr1h[g], Qr1h[4 + g]};
  h8 q1l[2] = {Qr1l[g], Qr1l[4 + g]};

  // K staging: pre-swizzled per-lane global byte offsets (linear LDS dest)
  const int s0i = wu * 128 + lane;
  const int s1i = s0i + 64;
  const int ko0 = (s0i >> 3) * 128 + (((s0i & 7) ^ ((s0i >> 3) & 7)) << 4);
  const int ko1 = (s1i >> 3) * 128 + (((s1i & 7) ^ ((s1i >> 3) & 7)) << 4);

  // ---- stage rel tables as fp16 chunks: rel_h -> KH0, rel_w -> KL0 ----
  #pragma unroll
  for (int it = 0; it < 2; ++it) {
    int task = tid + it * 256;
    int oct = task & 7, s = task >> 3;
    int ss = s < 63 ? s : 62;
    const float* sh = rel_h + (size_t)ss * DH + oct * 8;
    const float* sw = rel_w + (size_t)ss * DH + oct * 8;
    h8 hh, ww;
    #pragma unroll
    for (int e = 0; e < 8; ++e) {
      hh[e] = (_Float16)sh[e];
      ww[e] = (_Float16)sw[e];
    }
    int byo = s * 128 + ((oct ^ (s & 7)) << 4);
    *(h8*)(SMem + byo) = hh;
    *(h8*)(SMem + 16384 + byo) = ww;
  }
  __syncthreads();

  // ---- lh/lw tables via swapped MFMA: D[s-local=4g+reg][i=c] ----
  const int yi = (i0 + w * 32) >> 5;   // same for both rowsets
  f4 zf = {0.f, 0.f, 0.f, 0.f};
  #pragma unroll
  for (int rs = 0; rs < 2; ++rs) {
    f4 lhD[4], lwD[4], lhDc[4], lwDc[4];
    #pragma unroll
    for (int st = 0; st < 4; ++st) { lhD[st] = zf; lwD[st] = zf; lhDc[st] = zf; lwDc[st] = zf; }
    #pragma unroll
    for (int kh = 0; kh < 2; ++kh) {
      h8 bq = rs ? q1h[kh] : q0h[kh];
      h8 bl = rs ? q1l[kh] : q0l[kh];
      #pragma unroll
      for (int st = 0; st < 4; ++st) {
        int srow = st * 16 + c;
        int chb = srow * 128 + (((kh * 4 + g) ^ (srow & 7)) << 4);
        h8 ra = *(const h8*)(SMem + chb);
        h8 wa = *(const h8*)(SMem + 16384 + chb);
        lhD[st]  = __builtin_amdgcn_mfma_f32_16x16x32_f16(ra, bq, lhD[st], 0, 0, 0);
        lhDc[st] = __builtin_amdgcn_mfma_f32_16x16x32_f16(ra, bl, lhDc[st], 0, 0, 0);
        lwD[st]  = __builtin_amdgcn_mfma_f32_16x16x32_f16(wa, bq, lwD[st], 0, 0, 0);
        lwDc[st] = __builtin_amdgcn_mfma_f32_16x16x32_f16(wa, bl, lwDc[st], 0, 0, 0);
      }
    }
    int lrow = w * 32 + rs * 16 + c;
    #pragma unroll
    for (int st = 0; st < 4; ++st)
      #pragma unroll
      for (int reg = 0; reg < 4; ++reg) {
        int s = st * 16 + 4 * g + reg;
        float lhv = lhD[st][reg] + lhDc[st][reg] * INV_LOSCALE;
        float lwv = lwD[st][reg] + lwDc[st][reg] * INV_LOSCALE;
        int k = s - 31 + yi;
        if (k >= 0 && k < 32) LHc[k * 128 + lrow] = (_Float16)lhv;
        LWT[lrow * 64 + s] = (_Float16)lwv;
      }
  }
  __syncthreads();

  // lw registers: lwp[rs][jbp*4+reg] = lw[i][31 + jbp*16 + 4g+reg - xi]
  h8 lwp0, lwp1;
  #pragma unroll
  for (int jbp = 0; jbp < 2; ++jbp)
    #pragma unroll
    for (int reg = 0; reg < 4; ++reg) {
      lwp0[jbp * 4 + reg] = LWT[(w * 32 + c) * 64 + 31 + jbp * 16 + 4 * g + reg - c];
      lwp1[jbp * 4 + reg] = LWT[(w * 32 + 16 + c) * 64 + 31 + jbp * 16 + 4 * g + reg - 16 - c];
    }
  __syncthreads();

  // ---- stage tile 0 (K gloads -> buf0; V reg->LDS buf0) ----
  {
    gload_lds16((const char*)Khg + ko0, SMem + wu * 2048);
    gload_lds16((const char*)Khg + ko1, SMem + wu * 2048 + 1024);
    gload_lds16((const char*)Klg + ko0, SMem + 16384 + wu * 2048);
    gload_lds16((const char*)Klg + ko1, SMem + 16384 + wu * 2048 + 1024);
    int jp = tid & 31, dd = tid >> 5;
    const h8* vr = (const h8*)(Vg + (size_t)(2 * jp) * DH);
    h8 v0 = vr[dd], v1 = vr[8 + dd];
    us8 u0 = *(const us8*)&v0, u1 = *(const us8*)&v1;
    #pragma unroll
    for (int e = 0; e < 8; ++e) {
      int d = dd * 8 + e;
      unsigned int val = (unsigned int)u0[e] | ((unsigned int)u1[e] << 16);
      *(unsigned int*)(SMem + 32768 + d * 128 + (((jp >> 2) ^ (d & 7)) << 4) + (jp & 3) * 4) = val;
    }
  }
  __syncthreads();

  float m0 = -1e30f, m1 = -1e30f, lp0 = 0.f, lp1 = 0.f;
  f4 o0_[4], o1_[4];
  #pragma unroll
  for (int dt = 0; dt < 4; ++dt) { o0_[dt] = zf; o1_[dt] = zf; }

  int cur = 0;
  #pragma unroll 1
  for (int t = 0; t < 16; ++t) {
    char* Kc  = SMem + cur * 8192;
    char* KLc = SMem + 16384 + cur * 8192;
    char* Vc  = SMem + 32768 + cur * 8192;
    const int nxt = cur ^ 1;
    const bool pre = t < 15;
    const int jp = tid & 31, dd = tid >> 5;
    h8 v0 = {}, v1 = {};
    if (pre) {   // issue next-tile loads early (latency hides under QK)
      const char* kg  = (const char*)Khg + (size_t)(t + 1) * 8192;
      const char* klg = (const char*)Klg + (size_t)(t + 1) * 8192;
      gload_lds16(kg + ko0, SMem + nxt * 8192 + wu * 2048);
      gload_lds16(kg + ko1, SMem + nxt * 8192 + wu * 2048 + 1024);
      gload_lds16(klg + ko0, SMem + 16384 + nxt * 8192 + wu * 2048);
      gload_lds16(klg + ko1, SMem + 16384 + nxt * 8192 + wu * 2048 + 1024);
      const h8* vr = (const h8*)(Vg + (size_t)((t + 1) * 64 + 2 * jp) * DH);
      v0 = vr[dd];
      v1 = vr[8 + dd];
    }

    // ---- QK^T swapped: sX[jb][reg] = S[i = base+c][j = t*64+jb*16+4g+reg]
    f4 s0[4], c0[4], s1[4], c1[4];
    #pragma unroll
    for (int jb = 0; jb < 4; ++jb) { s0[jb] = zf; c0[jb] = zf; s1[jb] = zf; c1[jb] = zf; }
    #pragma unroll
    for (int kh = 0; kh < 2; ++kh) {
      h8 b0h = q0h[kh], b0l = q0l[kh], b1h = q1h[kh], b1l = q1l[kh];
      #pragma unroll
      for (int jb = 0; jb < 4; ++jb) {
        int jrow = jb * 16 + c;
        int chb = jrow * 128 + (((kh * 4 + g) ^ (c & 7)) << 4);
        h8 ah = *(const h8*)(Kc + chb);
        h8 al = *(const h8*)(KLc + chb);
        __builtin_amdgcn_s_setprio(1);
        s0[jb] = __builtin_amdgcn_mfma_f32_16x16x32_f16(ah, b0h, s0[jb], 0, 0, 0);
        c0[jb] = __builtin_amdgcn_mfma_f32_16x16x32_f16(al, b0h, c0[jb], 0, 0, 0);
        c0[jb] = __builtin_amdgcn_mfma_f32_16x16x32_f16(ah, b0l, c0[jb], 0, 0, 0);
        s1[jb] = __builtin_amdgcn_mfma_f32_16x16x32_f16(ah, b1h, s1[jb], 0, 0, 0);
        c1[jb] = __builtin_amdgcn_mfma_f32_16x16x32_f16(al, b1h, c1[jb], 0, 0, 0);
        c1[jb] = __builtin_amdgcn_mfma_f32_16x16x32_f16(ah, b1l, c1[jb], 0, 0, 0);
        __builtin_amdgcn_s_setprio(0);
      }
    }

    // finish: bias + online softmax (scalar state) + packed b64 P write
    auto finish = [&](f4* s_, f4* c_, const h8& lwp, float& m_s, float& lp,
                      f4* o_, int rs) {
      int rr = w * 32 + rs * 16 + c;
      float lh01[2] = {(float)LHc[(2 * t) * 128 + rr],
                       (float)LHc[(2 * t + 1) * 128 + rr]};
      #pragma unroll
      for (int jb = 0; jb < 4; ++jb)
        #pragma unroll
        for (int reg = 0; reg < 4; ++reg)
          s_[jb][reg] += c_[jb][reg] * INV_LOSCALE +
                         (float)lwp[(jb & 1) * 4 + reg] + lh01[jb >> 1];
      f4 ab = max4(s_[0], s_[1]);
      f4 cd = max4(s_[2], s_[3]);
      f4 ef = max4(ab, cd);
      float mx = fmaxf(fmaxf(ef[0], ef[1]), fmaxf(ef[2], ef[3]));
      mx = fmaxf(mx, __shfl_xor(mx, 16, 64));
      mx = fmaxf(mx, __shfl_xor(mx, 32, 64));
      bool sk = mx <= m_s + DTHR;      // T13 defer-max
      if (!__all(sk)) {
        float mn = fmaxf(m_s, mx);
        float corr = fexp2(m_s - mn);
        m_s = mn;
        lp *= corr;
        #pragma unroll
        for (int dt = 0; dt < 4; ++dt)
          #pragma unroll
          for (int reg = 0; reg < 4; ++reg)
            o_[dt][reg] *= corr;
      }
      float sum = 0.f;
      char* pbse = SP + w * 2048 + c * 128;
      #pragma unroll
      for (int jb = 0; jb < 4; ++jb) {
        f4 p;
        #pragma unroll
        for (int reg = 0; reg < 4; ++reg) {
          p[reg] = fexp2(s_[jb][reg] - m_s);
          sum += p[reg];
        }
        unsigned long long u = (unsigned long long)pk16(p[0], p[1]) |
                               ((unsigned long long)pk16(p[2], p[3]) << 32);
        *(unsigned long long*)(pbse + ((jb * 32 + 8 * g) ^ swz)) = u;
      }
      lp += sum;
    };

    finish(s0, c0, lwp0, m0, lp0, o0_, 0);
    __builtin_amdgcn_wave_barrier();

    // ---- PV rowset0 (swapped: A=V, B=P), cache V fragments; finish1's
    //      VALU is free to co-schedule with these MFMAs (no wave_barrier) ----
    h8 vbr[2][4];
    #pragma unroll
    for (int kh = 0; kh < 2; ++kh) {
      int och = ((kh * 4 + g) ^ (c & 7)) << 4;
      h8 pb = *(const h8*)(SP + w * 2048 + c * 128 + och);
      __builtin_amdgcn_s_setprio(1);
      #pragma unroll
      for (int dt = 0; dt < 4; ++dt) {
        vbr[kh][dt] = *(const h8*)(Vc + (dt * 16 + c) * 128 + och);
        o0_[dt] = __builtin_amdgcn_mfma_f32_16x16x32_f16(vbr[kh][dt], pb, o0_[dt], 0, 0, 0);
      }
      __builtin_amdgcn_s_setprio(0);
    }

    finish(s1, c1, lwp1, m1, lp1, o1_, 1);
    __builtin_amdgcn_wave_barrier();

    // ---- PV rowset1 (reuse V fragments) ----
    #pragma unroll
    for (int kh = 0; kh < 2; ++kh) {
      int och = ((kh * 4 + g) ^ (c & 7)) << 4;
      h8 pb = *(const h8*)(SP + w * 2048 + c * 128 + och);
      __builtin_amdgcn_s_setprio(1);
      #pragma unroll
      for (int dt = 0; dt < 4; ++dt)
        o1_[dt] = __builtin_amdgcn_mfma_f32_16x16x32_f16(vbr[kh][dt], pb, o1_[dt], 0, 0, 0);
      __builtin_amdgcn_s_setprio(0);
    }

    if (pre) {   // T14: write prefetched V after compute
      us8 u0 = *(const us8*)&v0, u1 = *(const us8*)&v1;
      char* Vn = SMem + 32768 + nxt * 8192;
      #pragma unroll
      for (int e = 0; e < 8; ++e) {
        int d = dd * 8 + e;
        unsigned int val = (unsigned int)u0[e] | ((unsigned int)u1[e] << 16);
        *(unsigned int*)(Vn + d * 128 + (((jp >> 2) ^ (d & 7)) << 4) + (jp & 3) * 4) = val;
      }
    }
    __syncthreads();
    cur = nxt;
  }

  // ---- epilogue: reduce l across g, normalize, transpose via OT, store ----
  float a0 = lp0;
  a0 += __shfl_xor(a0, 16, 64);
  a0 += __shfl_xor(a0, 32, 64);
  float r0 = __builtin_amdgcn_rcpf(a0);
  float a1 = lp1;
  a1 += __shfl_xor(a1, 16, 64);
  a1 += __shfl_xor(a1, 32, 64);
  float r1 = __builtin_amdgcn_rcpf(a1);
  #pragma unroll
  for (int dt = 0; dt < 4; ++dt)
    #pragma unroll
    for (int reg = 0; reg < 4; ++reg) {
      int d = dt * 16 + 4 * g + reg;
      int sw = (d & 7) << 3;
      int il0 = w * 32 + c;
      OT[d * 128 + (il0 ^ sw)] = o0_[dt][reg] * r0;
      OT[d * 128 + ((il0 + 16) ^ sw)] = o1_[dt][reg] * r1;
    }
  __syncthreads();
  #pragma unroll
  for (int it = 0; it < 8; ++it) {
    int task = tid + it * 256;
    int rq = task & 31, d = task >> 5;
    f4 vv = *(const f4*)&OT[d * 128 + ((rq * 4) ^ ((d & 7) << 3))];
    *(f4*)(out + (((size_t)bh * 64 + d) << 10) + i0 + rq * 4) = vv;
  }
}

extern "C" void kernel_launch(void* const* d_in, const int* in_sizes, int n_in,
                              void* d_out, int out_size, void* d_ws, size_t ws_size,
                              hipStream_t stream) {
  const float* x  = (const float*)d_in[0];
  const float* wq = (const float*)d_in[1];
  const float* rh = (const float*)d_in[2];
  const float* rw = (const float*)d_in[3];
  float* out = (float*)d_out;

  const size_t sz = (size_t)NBH * NPIX * DH;
  _Float16* Qh = (_Float16*)d_ws;
  _Float16* Ql = Qh + sz;
  _Float16* Kh = Ql + sz;
  _Float16* Kl = Kh + sz;
  _Float16* V  = Kl + sz;

  qkv_mfma<<<dim3(12, 16, 8), 256, 0, stream>>>(x, wq, Qh, Ql, Kh, Kl, V);
  attn_mfma<<<dim3(512), 256, 0, stream>>>(Qh, Ql, Kh, Kl, V, rh, rw, out);
}